// Round 5
// baseline (14811.139 us; speedup 1.0000x reference)
//
#include <hip/hip_runtime.h>
#include <hip/hip_cooperative_groups.h>
#include <math.h>

namespace cg = cooperative_groups;

#define T_IN   12
#define T_OUT  12
#define NB     8192          /* 512 nodes x 16 batch, row id = n*16+b */
#define EPSV   1e-6f

typedef __attribute__((ext_vector_type(8))) short short8;
typedef __attribute__((ext_vector_type(4))) float floatx4;

// ---------------------------------------------------------------------------
// bf16 helpers. P-format: uint = (lo_bf16 << 16) | hi_bf16, value ~ hi + lo.
// ---------------------------------------------------------------------------
__device__ __forceinline__ unsigned short f2bf(float x) {     // RNE (setup packs)
    union { float f; unsigned u; } v; v.f = x;
    unsigned r = v.u + 0x7fffu + ((v.u >> 16) & 1u);
    return (unsigned short)(r >> 16);
}
__device__ __forceinline__ float bf2f(unsigned short h) {
    union { float f; unsigned u; } v; v.u = ((unsigned)h) << 16;
    return v.f;
}
__device__ __forceinline__ unsigned packbf(float v) {         // trunc split (hot path)
    unsigned u = __float_as_uint(v);
    unsigned hu = u & 0xffff0000u;
    float r = v - __uint_as_float(hu);
    unsigned ru = __float_as_uint(r);
    return (ru & 0xffff0000u) | (u >> 16);
}

__device__ __forceinline__ float sigmoid_fast(float x) {
    return 1.0f / (1.0f + __expf(-x));
}
__device__ __forceinline__ float tanh_fast(float x) {
    float e = __expf(2.0f * x);
    return 1.0f - 2.0f / (e + 1.0f);
}

// ---------------------------------------------------------------------------
// Descriptors
// ---------------------------------------------------------------------------
struct HopA {                    // fp32 setup GEMM (W^2 build)
    const float* M[4];
    float* dst0[4];
};

struct WPack { const float* w[4]; unsigned short* hi[4]; unsigned short* lo[4]; };

struct LPack {                   // lin-weight fragment pack
    const float* W; unsigned short* hi; unsigned short* lo;
    int base[10]; int nseg;
};

struct Params {
    const unsigned short* Whi[4]; const unsigned short* Wlo[4]; // hop A packs
    const float* M32[4];                                        // fp32 hop mats (xhop)
    unsigned* HA[4]; unsigned* HB[4]; unsigned* HG[4];          // hop outputs (P-format)
    float* HXS[4];
    unsigned *h0P, *h1P, *GP;
    float *h0, *h1, *Z;
    const float* xenc; float* di;
    const unsigned short* LWh[6]; const unsigned short* LWl[6]; // r0,z0,n0,r1,z1,n1
    const float* WOx[3];      // fp32 Wr0,Wz0,Wn0 (scalar-row part, cell0 only)
    const float* bias[6];
    const float* Wp; const float* bp; float* out;
};

// ---------------------------------------------------------------------------
// Setup kernels (ordinary launches, once per call)
// ---------------------------------------------------------------------------
__global__ void sums_kernel(const float* __restrict__ A, float* __restrict__ rs,
                            float* __restrict__ cs) {
    int i = blockIdx.x;
    int t = threadIdx.x;
    __shared__ float s1[256], s2[256];
    float a = A[i * 512 + t] + A[i * 512 + t + 256];
    float b = A[t * 512 + i] + A[(t + 256) * 512 + i];
    s1[t] = a; s2[t] = b;
    __syncthreads();
    for (int off = 128; off > 0; off >>= 1) {
        if (t < off) { s1[t] += s1[t + off]; s2[t] += s2[t + off]; }
        __syncthreads();
    }
    if (t == 0) { rs[i] = s1[0]; cs[i] = s2[0]; }
}

__global__ void fill_kernel(const float* __restrict__ A, const float* __restrict__ rs,
                            const float* __restrict__ cs, float* __restrict__ Wf,
                            float* __restrict__ Wb) {
    int i = blockIdx.x;
    float irs = 1.0f / (rs[i] + EPSV);
    float ics = 1.0f / (cs[i] + EPSV);
    for (int j = threadIdx.x; j < 512; j += 256) {
        Wf[i * 512 + j] = A[i * 512 + j] * irs;
        Wb[i * 512 + j] = A[j * 512 + i] * ics;
    }
}

__global__ void xenc_kernel(const float* __restrict__ x, float* __restrict__ xenc) {
    int idx = blockIdx.x * 256 + threadIdx.x;
    if (idx >= T_IN * NB) return;
    int j = idx & 511;
    int b = (idx >> 9) & 15;
    int t = idx >> 13;
    xenc[t * NB + j * 16 + b] = x[(b * T_IN + t) * 512 + j];
}

// fp32 GEMM for the setup-only W^2 = W @ W build. 64x64 tile, 4x4 micro.
__global__ __launch_bounds__(256) void ghop_kernel(HopA a) {
    int z = blockIdx.z;
    const float* Wm = a.M[z];
    const float* X = Wm;
    float* Y = a.dst0[z];
    int col0 = blockIdx.x * 64;
    int row0 = blockIdx.y * 64;
    int tid = threadIdx.x;
    int tx = tid & 15, ty = tid >> 4;
    int kkA = tid & 15, rrA = tid >> 4;
    int ccB = tid & 63, kkB = tid >> 6;

    __shared__ float As[16][68], Bs[16][68];
    float acc[4][4] = {};

    const float* wp = Wm + (row0 + rrA) * 512 + kkA;
    const float* xp = X + (size_t)(col0 + ccB) + (size_t)kkB * 512;

    float ra[4], rb[4];
#pragma unroll
    for (int p = 0; p < 4; ++p) ra[p] = wp[p * 16 * 512];
#pragma unroll
    for (int p = 0; p < 4; ++p) rb[p] = xp[(size_t)(p * 4) * 512];

    for (int k0 = 0; k0 < 512; k0 += 16) {
#pragma unroll
        for (int p = 0; p < 4; ++p) As[kkA][rrA + p * 16] = ra[p];
#pragma unroll
        for (int p = 0; p < 4; ++p) Bs[kkB + p * 4][ccB] = rb[p];
        __syncthreads();
        if (k0 + 16 < 512) {
            int kn = k0 + 16;
#pragma unroll
            for (int p = 0; p < 4; ++p) ra[p] = wp[p * 16 * 512 + kn];
#pragma unroll
            for (int p = 0; p < 4; ++p) rb[p] = xp[(size_t)(kn + p * 4) * 512];
        }
#pragma unroll
        for (int k = 0; k < 16; ++k) {
            const float4 a4 = *(const float4*)&As[k][ty * 4];
            const float4 b4 = *(const float4*)&Bs[k][tx * 4];
            float av[4] = { a4.x, a4.y, a4.z, a4.w };
            float bv[4] = { b4.x, b4.y, b4.z, b4.w };
#pragma unroll
            for (int i = 0; i < 4; ++i)
#pragma unroll
                for (int j = 0; j < 4; ++j)
                    acc[i][j] = fmaf(av[i], bv[j], acc[i][j]);
        }
        __syncthreads();
    }

    int colw = col0 + tx * 4;
#pragma unroll
    for (int i = 0; i < 4; ++i) {
        int row = row0 + ty * 4 + i;
        *(float4*)&Y[(size_t)row * 512 + colw] =
            make_float4(acc[i][0], acc[i][1], acc[i][2], acc[i][3]);
    }
}

// Pack W (512x512 fp32) into A-fragment-contiguous bf16 hi/lo (for hops)
__global__ void wpack_kernel(WPack a) {
    int z = blockIdx.y;
    int idx = blockIdx.x * 256 + threadIdx.x;   // 0..262143
    int m = idx >> 9, k = idx & 511;
    float x = a.w[z][idx];
    unsigned short h = f2bf(x);
    unsigned short l = f2bf(x - bf2f(h));
    int p = (((m >> 4) * 64 + (k >> 3)) * 16 + (m & 15)) * 8 + (k & 7);
    a.hi[z][p] = h;
    a.lo[z][p] = l;
}

// Pack lin weights (K x 64) into B-fragment order over len-64 segments.
__global__ void lpack_kernel(LPack p) {
    int idx = blockIdx.x * 256 + threadIdx.x;
    if (idx >= p.nseg * 4096) return;
    int j = idx & 7, ln = (idx >> 3) & 15, ntl = (idx >> 7) & 3, O = idx >> 9;
    int s = O >> 3, o8 = O & 7;
    int row = p.base[s] + o8 * 8 + j;
    int col = ntl * 16 + ln;
    float v = p.W[(size_t)row * 64 + col];
    unsigned short h = f2bf(v);
    p.hi[idx] = h;
    p.lo[idx] = f2bf(v - bf2f(h));
}

// ---------------------------------------------------------------------------
// Persistent-kernel device pieces
// ---------------------------------------------------------------------------

// 64m x 64n x 512k MFMA hop tile; X,Y P-format 512x1024; 4 waves as 2x2.
__device__ __forceinline__ void hop_tile(
    const unsigned short* __restrict__ Ahi, const unsigned short* __restrict__ Alo,
    const unsigned* __restrict__ X, unsigned* __restrict__ Y,
    int bm, int c0,
    unsigned short (*Bhi_s)[40], unsigned short (*Blo_s)[40]) {
    int tid = threadIdx.x;
    int lane = tid & 63, w = tid >> 6;
    int wm = (w & 1) * 32, wn = (w >> 1) * 32;
    int ln = lane & 15, quad = lane >> 4;
    int sc = tid & 63, skh = tid >> 6;

    floatx4 acc[2][2];
#pragma unroll
    for (int mi = 0; mi < 2; ++mi)
#pragma unroll
        for (int ci = 0; ci < 2; ++ci) acc[mi][ci] = (floatx4)0.0f;

    const unsigned* xbase = X + c0 + sc;
    int mtb = (bm + wm) >> 4;

    unsigned uv[8];
#pragma unroll
    for (int j = 0; j < 8; ++j)
        uv[j] = xbase[(size_t)(skh * 8 + j) * 1024];

    for (int k0 = 0; k0 < 512; k0 += 32) {
        short8 h8, l8;
#pragma unroll
        for (int j = 0; j < 8; ++j) {
            h8[j] = (short)(uv[j] & 0xffffu);
            l8[j] = (short)(uv[j] >> 16);
        }
        __syncthreads();
        *(short8*)&Bhi_s[sc][skh * 8] = h8;
        *(short8*)&Blo_s[sc][skh * 8] = l8;
        __syncthreads();
        if (k0 + 32 < 512) {
            int kn = k0 + 32;
#pragma unroll
            for (int j = 0; j < 8; ++j)
                uv[j] = xbase[(size_t)(kn + skh * 8 + j) * 1024];
        }
        short8 bh[2], bl[2];
#pragma unroll
        for (int ci = 0; ci < 2; ++ci) {
            bh[ci] = *(const short8*)&Bhi_s[wn + ci * 16 + ln][quad * 8];
            bl[ci] = *(const short8*)&Blo_s[wn + ci * 16 + ln][quad * 8];
        }
        int kob = (k0 >> 3) + quad;
#pragma unroll
        for (int mi = 0; mi < 2; ++mi) {
            size_t aoff = ((size_t)((mtb + mi) * 64 + kob) * 16 + ln) * 8;
            short8 Ah = *(const short8*)(Ahi + aoff);
            short8 Al = *(const short8*)(Alo + aoff);
#pragma unroll
            for (int ci = 0; ci < 2; ++ci) {
                acc[mi][ci] = __builtin_amdgcn_mfma_f32_16x16x32_bf16(Ah, bh[ci], acc[mi][ci], 0, 0, 0);
                acc[mi][ci] = __builtin_amdgcn_mfma_f32_16x16x32_bf16(Ah, bl[ci], acc[mi][ci], 0, 0, 0);
                acc[mi][ci] = __builtin_amdgcn_mfma_f32_16x16x32_bf16(Al, bh[ci], acc[mi][ci], 0, 0, 0);
            }
        }
    }

#pragma unroll
    for (int mi = 0; mi < 2; ++mi) {
#pragma unroll
        for (int ci = 0; ci < 2; ++ci) {
            int mrow = bm + wm + mi * 16 + quad * 4;
            int col = c0 + wn + ci * 16 + ln;
#pragma unroll
            for (int r = 0; r < 4; ++r)
                Y[(size_t)(mrow + r) * 1024 + col] = packbf(acc[mi][ci][r]);
        }
    }
}

// tiny fp32 x-hop: 16 rows x 16 cols per job, K=512
__device__ __forceinline__ void xhop_job(const float* __restrict__ M,
                                         const float* __restrict__ xv,
                                         float* __restrict__ dst, int mt) {
    int m = mt * 16 + (threadIdx.x >> 4);
    int c = threadIdx.x & 15;
    const float* wrow = M + (size_t)m * 512;
    float s = 0.0f;
#pragma unroll 4
    for (int k = 0; k < 512; ++k)
        s = fmaf(wrow[k], xv[k * 16 + c], s);
    dst[m * 16 + c] = s;
}

// MFMA lin core: wave computes 16 rows x 64 cols, LDS-free.
__device__ __forceinline__ void lin_core(const unsigned* const* segs, int nseg,
        const unsigned short* __restrict__ Bh, const unsigned short* __restrict__ Bl,
        int row0, int ln, int quad, floatx4 acc[4]) {
    for (int s = 0; s < nseg; ++s) {
        const unsigned* ap = segs[s] + (size_t)(row0 + ln) * 64 + quad * 8;
#pragma unroll
        for (int hh = 0; hh < 2; ++hh) {
            unsigned u[8];
            *(uint4*)&u[0] = *(const uint4*)(ap + hh * 32);
            *(uint4*)&u[4] = *(const uint4*)(ap + hh * 32 + 4);
            short8 Ah, Al;
#pragma unroll
            for (int j = 0; j < 8; ++j) {
                Ah[j] = (short)(u[j] & 0xffffu);
                Al[j] = (short)(u[j] >> 16);
            }
            int O = s * 8 + hh * 4 + quad;
#pragma unroll
            for (int ci = 0; ci < 4; ++ci) {
                size_t boff = ((size_t)(O * 4 + ci) * 16 + ln) * 8;
                short8 B1 = *(const short8*)(Bh + boff);
                short8 B2 = *(const short8*)(Bl + boff);
                acc[ci] = __builtin_amdgcn_mfma_f32_16x16x32_bf16(Ah, B1, acc[ci], 0, 0, 0);
                acc[ci] = __builtin_amdgcn_mfma_f32_16x16x32_bf16(Al, B1, acc[ci], 0, 0, 0);
                acc[ci] = __builtin_amdgcn_mfma_f32_16x16x32_bf16(Ah, B2, acc[ci], 0, 0, 0);
            }
        }
    }
}

// scalar (len-1) K rows: cell0 only
__device__ __forceinline__ void lin_scalar(const float* const* sx, const int* sxrow,
        int nsx, const float* __restrict__ WO,
        int row0, int ln, int quad, floatx4 acc[4]) {
    for (int t = 0; t < nsx; ++t) {
        const float* wr = WO + (size_t)sxrow[t] * 64;
        const float* sv = sx[t] + row0 + quad * 4;
#pragma unroll
        for (int rr = 0; rr < 4; ++rr) {
            float v = sv[rr];
#pragma unroll
            for (int ci = 0; ci < 4; ++ci)
                acc[ci][rr] = fmaf(v, wr[ci * 16 + ln], acc[ci][rr]);
        }
    }
}

// ---------------------------------------------------------------------------
// The persistent cooperative kernel: whole encoder+decoder recurrence.
// ---------------------------------------------------------------------------
__global__ __launch_bounds__(256, 2) void dcrnn_coop(Params P) {
    cg::grid_group grid = cg::this_grid();
    __shared__ unsigned short Bhi_s[64][40];
    __shared__ unsigned short Blo_s[64][40];

    const int nb = gridDim.x;
    const int nwaves = nb * 4;
    const int gw = blockIdx.x * 4 + (threadIdx.x >> 6);
    const int lane = threadIdx.x & 63;
    const int ln = lane & 15, quad = lane >> 4;
    const int sxrow0[5] = { 0, 65, 130, 195, 260 };

    for (int t = 0; t < T_IN + T_OUT; ++t) {
        const float* xcur = (t <= T_IN) ? (P.xenc + (size_t)((t < T_IN) ? t : (T_IN - 1)) * NB)
                                        : P.di;
        const float* sx0[5] = { xcur, P.HXS[0], P.HXS[1], P.HXS[2], P.HXS[3] };
        int doProj = (t >= T_IN);
        int td = t - T_IN;

        // ---- cell0 stage 1: hops of h0 (MFMA) + hops of x (fp32) -----------
        for (int j = blockIdx.x; j < 640; j += nb) {
            if (j < 512) {
                int z = j & 3, rest = j >> 2;
                int bm = (rest & 7) * 64, c0 = (rest >> 3) * 64;
                hop_tile(P.Whi[z], P.Wlo[z], P.h0P, P.HB[z], bm, c0, Bhi_s, Blo_s);
            } else {
                int xj = j - 512;
                xhop_job(P.M32[xj & 3], xcur, P.HXS[xj & 3], xj >> 2);
            }
        }
        grid.sync();

        // ---- cell0 stage 2: r/z gates --------------------------------------
        {
            const unsigned* segs[5] = { P.h0P, P.HB[0], P.HB[1], P.HB[2], P.HB[3] };
            for (int j = gw; j < 1024; j += nwaves) {
                int gate = j >> 9;
                int row0 = (j & 511) << 4;
                floatx4 acc[4];
#pragma unroll
                for (int ci = 0; ci < 4; ++ci) acc[ci] = (floatx4)0.0f;
                lin_core(segs, 5, P.LWh[gate], P.LWl[gate], row0, ln, quad, acc);
                lin_scalar(sx0, sxrow0, 5, P.WOx[gate], row0, ln, quad, acc);
                const float* bias = P.bias[gate];
#pragma unroll
                for (int ci = 0; ci < 4; ++ci) {
                    int col = ci * 16 + ln;
                    float bv = bias[col];
#pragma unroll
                    for (int rr = 0; rr < 4; ++rr) {
                        int row = row0 + quad * 4 + rr;
                        size_t idx = (size_t)row * 64 + col;
                        float sg = sigmoid_fast(acc[ci][rr] + bv);
                        if (gate == 0) P.GP[idx] = packbf(sg * P.h0[idx]);
                        else P.Z[idx] = sg;
                    }
                }
            }
        }
        grid.sync();

        // ---- cell0 stage 3: hops of G -------------------------------------
        for (int j = blockIdx.x; j < 512; j += nb) {
            int z = j & 3, rest = j >> 2;
            int bm = (rest & 7) * 64, c0 = (rest >> 3) * 64;
            hop_tile(P.Whi[z], P.Wlo[z], P.GP, P.HG[z], bm, c0, Bhi_s, Blo_s);
        }
        grid.sync();

        // ---- cell0 stage 4: n gate + h0 update ----------------------------
        {
            const unsigned* segs[5] = { P.GP, P.HG[0], P.HG[1], P.HG[2], P.HG[3] };
            for (int j = gw; j < 512; j += nwaves) {
                int row0 = j << 4;
                floatx4 acc[4];
#pragma unroll
                for (int ci = 0; ci < 4; ++ci) acc[ci] = (floatx4)0.0f;
                lin_core(segs, 5, P.LWh[2], P.LWl[2], row0, ln, quad, acc);
                lin_scalar(sx0, sxrow0, 5, P.WOx[2], row0, ln, quad, acc);
                const float* bias = P.bias[2];
#pragma unroll
                for (int ci = 0; ci < 4; ++ci) {
                    int col = ci * 16 + ln;
                    float bv = bias[col];
#pragma unroll
                    for (int rr = 0; rr < 4; ++rr) {
                        int row = row0 + quad * 4 + rr;
                        size_t idx = (size_t)row * 64 + col;
                        float nn = tanh_fast(acc[ci][rr] + bv);
                        float z = P.Z[idx];
                        float o = (1.0f - z) * P.h0[idx] + z * nn;
                        P.h0[idx] = o;
                        P.h0P[idx] = packbf(o);
                    }
                }
            }
        }
        grid.sync();

        // ---- cell1 stage 1: hops of h0 -> HA, hops of h1 -> HB ------------
        for (int j = blockIdx.x; j < 1024; j += nb) {
            int jj = j & 511;
            int z = jj & 3, rest = jj >> 2;
            int bm = (rest & 7) * 64, c0 = (rest >> 3) * 64;
            if (j < 512) hop_tile(P.Whi[z], P.Wlo[z], P.h0P, P.HA[z], bm, c0, Bhi_s, Blo_s);
            else         hop_tile(P.Whi[z], P.Wlo[z], P.h1P, P.HB[z], bm, c0, Bhi_s, Blo_s);
        }
        grid.sync();

        // ---- cell1 stage 2: r/z gates -------------------------------------
        {
            const unsigned* segs[10] = { P.h0P, P.h1P,
                                         P.HA[0], P.HB[0], P.HA[1], P.HB[1],
                                         P.HA[2], P.HB[2], P.HA[3], P.HB[3] };
            for (int j = gw; j < 1024; j += nwaves) {
                int gate = j >> 9;
                int row0 = (j & 511) << 4;
                floatx4 acc[4];
#pragma unroll
                for (int ci = 0; ci < 4; ++ci) acc[ci] = (floatx4)0.0f;
                lin_core(segs, 10, P.LWh[3 + gate], P.LWl[3 + gate], row0, ln, quad, acc);
                const float* bias = P.bias[3 + gate];
#pragma unroll
                for (int ci = 0; ci < 4; ++ci) {
                    int col = ci * 16 + ln;
                    float bv = bias[col];
#pragma unroll
                    for (int rr = 0; rr < 4; ++rr) {
                        int row = row0 + quad * 4 + rr;
                        size_t idx = (size_t)row * 64 + col;
                        float sg = sigmoid_fast(acc[ci][rr] + bv);
                        if (gate == 0) P.GP[idx] = packbf(sg * P.h1[idx]);
                        else P.Z[idx] = sg;
                    }
                }
            }
        }
        grid.sync();

        // ---- cell1 stage 3: hops of G -------------------------------------
        for (int j = blockIdx.x; j < 512; j += nb) {
            int z = j & 3, rest = j >> 2;
            int bm = (rest & 7) * 64, c0 = (rest >> 3) * 64;
            hop_tile(P.Whi[z], P.Wlo[z], P.GP, P.HG[z], bm, c0, Bhi_s, Blo_s);
        }
        grid.sync();

        // ---- cell1 stage 4: n gate + h1 update (+ projection) -------------
        {
            const unsigned* segs[10] = { P.h0P, P.GP,
                                         P.HA[0], P.HG[0], P.HA[1], P.HG[1],
                                         P.HA[2], P.HG[2], P.HA[3], P.HG[3] };
            for (int j = gw; j < 512; j += nwaves) {
                int row0 = j << 4;
                floatx4 acc[4];
#pragma unroll
                for (int ci = 0; ci < 4; ++ci) acc[ci] = (floatx4)0.0f;
                lin_core(segs, 10, P.LWh[5], P.LWl[5], row0, ln, quad, acc);
                const float* bias = P.bias[5];
                float p[4] = { 0.0f, 0.0f, 0.0f, 0.0f };
#pragma unroll
                for (int ci = 0; ci < 4; ++ci) {
                    int col = ci * 16 + ln;
                    float bv = bias[col];
                    float wpv = doProj ? P.Wp[col] : 0.0f;
#pragma unroll
                    for (int rr = 0; rr < 4; ++rr) {
                        int row = row0 + quad * 4 + rr;
                        size_t idx = (size_t)row * 64 + col;
                        float nn = tanh_fast(acc[ci][rr] + bv);
                        float z = P.Z[idx];
                        float o = (1.0f - z) * P.h1[idx] + z * nn;
                        P.h1[idx] = o;
                        P.h1P[idx] = packbf(o);
                        p[rr] = fmaf(o, wpv, p[rr]);
                    }
                }
                if (doProj) {
#pragma unroll
                    for (int rr = 0; rr < 4; ++rr) {
                        p[rr] += __shfl_xor(p[rr], 1, 64);
                        p[rr] += __shfl_xor(p[rr], 2, 64);
                        p[rr] += __shfl_xor(p[rr], 4, 64);
                        p[rr] += __shfl_xor(p[rr], 8, 64);
                    }
                    if (ln == 0) {
                        float bpv = P.bp[0];
#pragma unroll
                        for (int rr = 0; rr < 4; ++rr) {
                            int row = row0 + quad * 4 + rr;
                            float y = p[rr] + bpv;
                            int n = row >> 4, b = row & 15;
                            P.out[(b * T_OUT + td) * 512 + n] = y;
                            P.di[row] = y;
                        }
                    }
                }
            }
        }
        grid.sync();
    }
}

// ---------------------------------------------------------------------------
extern "C" void kernel_launch(void* const* d_in, const int* in_sizes, int n_in,
                              void* d_out, int out_size, void* d_ws, size_t ws_size,
                              hipStream_t stream) {
    (void)in_sizes; (void)n_in; (void)out_size; (void)ws_size;
    const float* x   = (const float*)d_in[0];
    const float* A   = (const float*)d_in[1];
    const float* Wr0 = (const float*)d_in[2];  const float* br0 = (const float*)d_in[3];
    const float* Wz0 = (const float*)d_in[4];  const float* bz0 = (const float*)d_in[5];
    const float* Wn0 = (const float*)d_in[6];  const float* bn0 = (const float*)d_in[7];
    const float* Wr1 = (const float*)d_in[8];  const float* br1 = (const float*)d_in[9];
    const float* Wz1 = (const float*)d_in[10]; const float* bz1 = (const float*)d_in[11];
    const float* Wn1 = (const float*)d_in[12]; const float* bn1 = (const float*)d_in[13];
    const float* Wp  = (const float*)d_in[14]; const float* bp  = (const float*)d_in[15];
    float* out = (float*)d_out;

    float* ws = (float*)d_ws;
    size_t off = 0;
    auto alloc = [&](size_t nf) { float* p = ws + off; off += nf; return p; };
    float* Wf  = alloc(262144); float* Wb  = alloc(262144);
    float* W2f = alloc(262144); float* W2b = alloc(262144);
    float* rs  = alloc(512);    float* cs  = alloc(512);
    float* xenc = alloc((size_t)T_IN * NB);
    unsigned short* Whi[4]; unsigned short* Wlo[4];
    for (int m = 0; m < 4; ++m) Whi[m] = (unsigned short*)alloc(131072);
    for (int m = 0; m < 4; ++m) Wlo[m] = (unsigned short*)alloc(131072);
    unsigned* HA_P[4]; unsigned* HB_P[4]; unsigned* HG_P[4];
    for (int m = 0; m < 4; ++m) HA_P[m] = (unsigned*)alloc(524288);
    for (int m = 0; m < 4; ++m) HB_P[m] = (unsigned*)alloc(524288);
    for (int m = 0; m < 4; ++m) HG_P[m] = (unsigned*)alloc(524288);
    unsigned* GP  = (unsigned*)alloc(524288);
    unsigned* h0P = (unsigned*)alloc(524288);
    unsigned* h1P = (unsigned*)alloc(524288);
    float* Z  = alloc(524288);
    float* h0 = alloc(524288);
    float* h1 = alloc(524288);
    float* HXS[4];
    for (int m = 0; m < 4; ++m) HXS[m] = alloc(8192);
    float* di = alloc(8192);
    unsigned short* LWh[6]; unsigned short* LWl[6];
    for (int g = 0; g < 3; ++g) { LWh[g] = (unsigned short*)alloc(10240); LWl[g] = (unsigned short*)alloc(10240); }
    for (int g = 3; g < 6; ++g) { LWh[g] = (unsigned short*)alloc(20480); LWl[g] = (unsigned short*)alloc(20480); }

    hipMemsetAsync(h0, 0, 524288 * sizeof(float), stream);
    hipMemsetAsync(h1, 0, 524288 * sizeof(float), stream);
    hipMemsetAsync(h0P, 0, 524288 * sizeof(unsigned), stream);
    hipMemsetAsync(h1P, 0, 524288 * sizeof(unsigned), stream);

    xenc_kernel<<<dim3((T_IN * NB) / 256), 256, 0, stream>>>(x, xenc);
    sums_kernel<<<dim3(512), 256, 0, stream>>>(A, rs, cs);
    fill_kernel<<<dim3(512), 256, 0, stream>>>(A, rs, cs, Wf, Wb);

    { // W2f = Wf@Wf, W2b = Wb@Wb (fp32, setup only)
        HopA w2 = {};
        w2.M[0] = Wf; w2.M[1] = Wb;
        w2.dst0[0] = W2f; w2.dst0[1] = W2b;
        ghop_kernel<<<dim3(8, 8, 2), 256, 0, stream>>>(w2);
    }
    { // pack hop A-operands
        WPack p;
        p.w[0] = Wf; p.w[1] = W2f; p.w[2] = Wb; p.w[3] = W2b;
        for (int m = 0; m < 4; ++m) { p.hi[m] = Whi[m]; p.lo[m] = Wlo[m]; }
        wpack_kernel<<<dim3(1024, 4), 256, 0, stream>>>(p);
    }
    { // pack lin weights
        const float* WG[6] = { Wr0, Wz0, Wn0, Wr1, Wz1, Wn1 };
        for (int g = 0; g < 6; ++g) {
            LPack p = {};
            p.W = WG[g]; p.hi = LWh[g]; p.lo = LWl[g];
            if (g < 3) { p.nseg = 5;  for (int s = 0; s < 5; ++s)  p.base[s] = 65 * s + 1; }
            else       { p.nseg = 10; for (int s = 0; s < 10; ++s) p.base[s] = 64 * s; }
            lpack_kernel<<<dim3((p.nseg * 4096 + 255) / 256), 256, 0, stream>>>(p);
        }
    }

    // ---- persistent cooperative kernel for the whole recurrence ----------
    Params P;
    for (int m = 0; m < 4; ++m) { P.Whi[m] = Whi[m]; P.Wlo[m] = Wlo[m]; }
    P.M32[0] = Wf; P.M32[1] = W2f; P.M32[2] = Wb; P.M32[3] = W2b;
    for (int m = 0; m < 4; ++m) { P.HA[m] = HA_P[m]; P.HB[m] = HB_P[m]; P.HG[m] = HG_P[m]; }
    for (int m = 0; m < 4; ++m) P.HXS[m] = HXS[m];
    P.h0P = h0P; P.h1P = h1P; P.GP = GP;
    P.h0 = h0; P.h1 = h1; P.Z = Z;
    P.xenc = xenc; P.di = di;
    for (int g = 0; g < 6; ++g) { P.LWh[g] = LWh[g]; P.LWl[g] = LWl[g]; }
    P.WOx[0] = Wr0; P.WOx[1] = Wz0; P.WOx[2] = Wn0;
    P.bias[0] = br0; P.bias[1] = bz0; P.bias[2] = bn0;
    P.bias[3] = br1; P.bias[4] = bz1; P.bias[5] = bn1;
    P.Wp = Wp; P.bp = bp; P.out = out;

    int maxb = 0;
    if (hipOccupancyMaxActiveBlocksPerMultiprocessor(&maxb, dcrnn_coop, 256, 0)
            != hipSuccess || maxb < 1)
        maxb = 1;
    int nblocks = maxb * 256;
    if (nblocks > 512) nblocks = 512;

    void* args[] = { (void*)&P };
    hipLaunchCooperativeKernel((const void*)dcrnn_coop, dim3(nblocks), dim3(256),
                               args, 0, stream);
}

// Round 6
// 4059.115 us; speedup vs baseline: 3.6489x; 3.6489x over previous
//
#include <hip/hip_runtime.h>
#include <math.h>

#define T_IN   12
#define T_OUT  12
#define NB     8192          /* 512 nodes x 16 batch, row id = n*16+b */
#define EPSV   1e-6f

typedef __attribute__((ext_vector_type(8))) short short8;
typedef __attribute__((ext_vector_type(4))) float floatx4;

// ---------------------------------------------------------------------------
// bf16 helpers. P-format: uint = (lo_bf16 << 16) | hi_bf16, value ~ hi + lo.
// ---------------------------------------------------------------------------
__device__ __forceinline__ unsigned short f2bf(float x) {     // RNE (setup packs)
    union { float f; unsigned u; } v; v.f = x;
    unsigned r = v.u + 0x7fffu + ((v.u >> 16) & 1u);
    return (unsigned short)(r >> 16);
}
__device__ __forceinline__ float bf2f(unsigned short h) {
    union { float f; unsigned u; } v; v.u = ((unsigned)h) << 16;
    return v.f;
}
__device__ __forceinline__ unsigned packbf(float v) {         // trunc split (hot path)
    unsigned u = __float_as_uint(v);
    unsigned hu = u & 0xffff0000u;
    float r = v - __uint_as_float(hu);
    unsigned ru = __float_as_uint(r);
    return (ru & 0xffff0000u) | (u >> 16);
}

__device__ __forceinline__ float sigmoid_fast(float x) {
    return 1.0f / (1.0f + __expf(-x));
}
__device__ __forceinline__ float tanh_fast(float x) {
    float e = __expf(2.0f * x);
    return 1.0f - 2.0f / (e + 1.0f);
}

// ---------------------------------------------------------------------------
// Descriptors
// ---------------------------------------------------------------------------
struct HopA {                    // fp32 setup GEMM (W^2 build)
    const float* M[4];
    float* dst0[4];
};

struct HopM {                    // MFMA hop: Y[z] = M[z] @ X, X/Y in P-format
    const unsigned short* Ahi[4]; const unsigned short* Alo[4];
    const unsigned* src0; const unsigned* src1;
    unsigned* dst0[4]; unsigned* dst1[4];
    int tiles0;
};

struct XHopAll { const float* M[4]; const float* xenc; float* dst; };  // 12 slices
struct XHopOne { const float* M[4]; const float* xv; float* dst; };

struct WPack { const float* w[4]; unsigned short* hi[4]; unsigned short* lo[4]; };

struct LPack {                   // lin-weight fragment pack
    const float* W; unsigned short* hi; unsigned short* lo;
    int base[10]; int nseg;
};

struct LinA {                    // lin GEMM input descriptor
    const unsigned* seg[10]; int nseg;        // P-format (8192 x 64) segments
    const float* sx[5]; int sxrow[5]; int nsx; // scalar (len-1) segments, fp32
};

// ---------------------------------------------------------------------------
// Setup kernels
// ---------------------------------------------------------------------------
__global__ void sums_kernel(const float* __restrict__ A, float* __restrict__ rs,
                            float* __restrict__ cs) {
    int i = blockIdx.x;
    int t = threadIdx.x;
    __shared__ float s1[256], s2[256];
    float a = A[i * 512 + t] + A[i * 512 + t + 256];
    float b = A[t * 512 + i] + A[(t + 256) * 512 + i];
    s1[t] = a; s2[t] = b;
    __syncthreads();
    for (int off = 128; off > 0; off >>= 1) {
        if (t < off) { s1[t] += s1[t + off]; s2[t] += s2[t + off]; }
        __syncthreads();
    }
    if (t == 0) { rs[i] = s1[0]; cs[i] = s2[0]; }
}

__global__ void fill_kernel(const float* __restrict__ A, const float* __restrict__ rs,
                            const float* __restrict__ cs, float* __restrict__ Wf,
                            float* __restrict__ Wb) {
    int i = blockIdx.x;
    float irs = 1.0f / (rs[i] + EPSV);
    float ics = 1.0f / (cs[i] + EPSV);
    for (int j = threadIdx.x; j < 512; j += 256) {
        Wf[i * 512 + j] = A[i * 512 + j] * irs;
        Wb[i * 512 + j] = A[j * 512 + i] * ics;
    }
}

__global__ void xenc_kernel(const float* __restrict__ x, float* __restrict__ xenc) {
    int idx = blockIdx.x * 256 + threadIdx.x;
    if (idx >= T_IN * NB) return;
    int j = idx & 511;
    int b = (idx >> 9) & 15;
    int t = idx >> 13;
    xenc[t * NB + j * 16 + b] = x[(b * T_IN + t) * 512 + j];
}

// fp32 GEMM for the setup-only W^2 = W @ W build. 64x64 tile, 4x4 micro.
__global__ __launch_bounds__(256) void ghop_kernel(HopA a) {
    int z = blockIdx.z;
    const float* Wm = a.M[z];
    const float* X = Wm;
    float* Y = a.dst0[z];
    int col0 = blockIdx.x * 64;
    int row0 = blockIdx.y * 64;
    int tid = threadIdx.x;
    int tx = tid & 15, ty = tid >> 4;
    int kkA = tid & 15, rrA = tid >> 4;
    int ccB = tid & 63, kkB = tid >> 6;

    __shared__ float As[16][68], Bs[16][68];
    float acc[4][4] = {};

    const float* wp = Wm + (row0 + rrA) * 512 + kkA;
    const float* xp = X + (size_t)(col0 + ccB) + (size_t)kkB * 512;

    float ra[4], rb[4];
#pragma unroll
    for (int p = 0; p < 4; ++p) ra[p] = wp[p * 16 * 512];
#pragma unroll
    for (int p = 0; p < 4; ++p) rb[p] = xp[(size_t)(p * 4) * 512];

    for (int k0 = 0; k0 < 512; k0 += 16) {
#pragma unroll
        for (int p = 0; p < 4; ++p) As[kkA][rrA + p * 16] = ra[p];
#pragma unroll
        for (int p = 0; p < 4; ++p) Bs[kkB + p * 4][ccB] = rb[p];
        __syncthreads();
        if (k0 + 16 < 512) {
            int kn = k0 + 16;
#pragma unroll
            for (int p = 0; p < 4; ++p) ra[p] = wp[p * 16 * 512 + kn];
#pragma unroll
            for (int p = 0; p < 4; ++p) rb[p] = xp[(size_t)(kn + p * 4) * 512];
        }
#pragma unroll
        for (int k = 0; k < 16; ++k) {
            const float4 a4 = *(const float4*)&As[k][ty * 4];
            const float4 b4 = *(const float4*)&Bs[k][tx * 4];
            float av[4] = { a4.x, a4.y, a4.z, a4.w };
            float bv[4] = { b4.x, b4.y, b4.z, b4.w };
#pragma unroll
            for (int i = 0; i < 4; ++i)
#pragma unroll
                for (int j = 0; j < 4; ++j)
                    acc[i][j] = fmaf(av[i], bv[j], acc[i][j]);
        }
        __syncthreads();
    }

    int colw = col0 + tx * 4;
#pragma unroll
    for (int i = 0; i < 4; ++i) {
        int row = row0 + ty * 4 + i;
        *(float4*)&Y[(size_t)row * 512 + colw] =
            make_float4(acc[i][0], acc[i][1], acc[i][2], acc[i][3]);
    }
}

// Pack W (512x512 fp32) into A-fragment-contiguous bf16 hi/lo (for hops)
__global__ void wpack_kernel(WPack a) {
    int z = blockIdx.y;
    int idx = blockIdx.x * 256 + threadIdx.x;   // 0..262143
    int m = idx >> 9, k = idx & 511;
    float x = a.w[z][idx];
    unsigned short h = f2bf(x);
    unsigned short l = f2bf(x - bf2f(h));
    int p = (((m >> 4) * 64 + (k >> 3)) * 16 + (m & 15)) * 8 + (k & 7);
    a.hi[z][p] = h;
    a.lo[z][p] = l;
}

// Pack lin weights (K x 64) into B-fragment order over len-64 segments.
__global__ void lpack_kernel(LPack p) {
    int idx = blockIdx.x * 256 + threadIdx.x;
    if (idx >= p.nseg * 4096) return;
    int j = idx & 7, ln = (idx >> 3) & 15, ntl = (idx >> 7) & 3, O = idx >> 9;
    int s = O >> 3, o8 = O & 7;
    int row = p.base[s] + o8 * 8 + j;
    int col = ntl * 16 + ln;
    float v = p.W[(size_t)row * 64 + col];
    unsigned short h = f2bf(v);
    p.hi[idx] = h;
    p.lo[idx] = f2bf(v - bf2f(h));
}

// All 12 encoder x-hop slices: dst[(t*4+m)*NB + node*16+b]
__global__ void xhop_all_kernel(XHopAll a) {
    int t = blockIdx.z, mz = blockIdx.y;
    int m = blockIdx.x * 16 + (threadIdx.x >> 4);
    int c = threadIdx.x & 15;
    const float* wrow = a.M[mz] + (size_t)m * 512;
    const float* xv = a.xenc + (size_t)t * NB;
    float s = 0.0f;
#pragma unroll 4
    for (int k = 0; k < 512; ++k)
        s = fmaf(wrow[k], xv[k * 16 + c], s);
    a.dst[((size_t)t * 4 + mz) * NB + m * 16 + c] = s;
}

// Single decoder x-hop: dst[m*NB...] for 4 mats
__global__ void xhop_one_kernel(XHopOne a) {
    int mz = blockIdx.y;
    int m = blockIdx.x * 16 + (threadIdx.x >> 4);
    int c = threadIdx.x & 15;
    const float* wrow = a.M[mz] + (size_t)m * 512;
    float s = 0.0f;
#pragma unroll 4
    for (int k = 0; k < 512; ++k)
        s = fmaf(wrow[k], a.xv[k * 16 + c], s);
    a.dst[(size_t)mz * NB + m * 16 + c] = s;
}

// ---------------------------------------------------------------------------
// MFMA hop GEMM: Y[z](512x1024) = M[z](512x512) @ X(512x1024); X,Y P-format.
// Split-bf16 3-pass. Block tile (MI*32)m x 64n x 32k, 4 waves as 2x2,
// wave tile (MI*16)m x 32n. Double-buffered LDS, ONE barrier per k-chunk.
// ---------------------------------------------------------------------------
template<int MI>
__global__ __launch_bounds__(256) void hop_mfma(HopM a) {
    int z = blockIdx.z;
    int nt = blockIdx.x;
    const unsigned* X; unsigned* Y; int c0;
    if (nt < a.tiles0) { X = a.src0; Y = a.dst0[z]; c0 = nt * 64; }
    else { X = a.src1; Y = a.dst1[z]; c0 = (nt - a.tiles0) * 64; }
    const unsigned short* Ahi = a.Ahi[z];
    const unsigned short* Alo = a.Alo[z];
    int bm = blockIdx.y * (MI * 32);

    __shared__ unsigned short Bhi_s[2][64][40];
    __shared__ unsigned short Blo_s[2][64][40];

    int tid = threadIdx.x;
    int lane = tid & 63, w = tid >> 6;
    int wm = (w & 1) * (MI * 16), wn = (w >> 1) * 32;
    int ln = lane & 15, quad = lane >> 4;
    int sc = tid & 63, skh = tid >> 6;

    floatx4 acc[MI][2];
#pragma unroll
    for (int mi = 0; mi < MI; ++mi)
#pragma unroll
        for (int ci = 0; ci < 2; ++ci) acc[mi][ci] = (floatx4)0.0f;

    const unsigned* xbase = X + c0 + sc;
    int mtb = (bm + wm) >> 4;

    unsigned uv[8];
    // chunk 0 -> buf 0 (no barrier needed before first loop barrier)
#pragma unroll
    for (int j = 0; j < 8; ++j)
        uv[j] = xbase[(size_t)(skh * 8 + j) * 1024];
    {
        short8 h8, l8;
#pragma unroll
        for (int j = 0; j < 8; ++j) {
            h8[j] = (short)(uv[j] & 0xffffu);
            l8[j] = (short)(uv[j] >> 16);
        }
        *(short8*)&Bhi_s[0][sc][skh * 8] = h8;
        *(short8*)&Blo_s[0][sc][skh * 8] = l8;
    }
    // chunk 1 -> regs
#pragma unroll
    for (int j = 0; j < 8; ++j)
        uv[j] = xbase[(size_t)(32 + skh * 8 + j) * 1024];

    for (int it = 0; it < 16; ++it) {
        __syncthreads();
        int cur = it & 1;
        if (it + 1 < 16) {                  // stage chunk it+1 into other buf
            short8 h8, l8;
#pragma unroll
            for (int j = 0; j < 8; ++j) {
                h8[j] = (short)(uv[j] & 0xffffu);
                l8[j] = (short)(uv[j] >> 16);
            }
            *(short8*)&Bhi_s[cur ^ 1][sc][skh * 8] = h8;
            *(short8*)&Blo_s[cur ^ 1][sc][skh * 8] = l8;
        }
        if (it + 2 < 16) {                  // prefetch chunk it+2
            int kn = (it + 2) * 32;
#pragma unroll
            for (int j = 0; j < 8; ++j)
                uv[j] = xbase[(size_t)(kn + skh * 8 + j) * 1024];
        }
        short8 bh[2], bl[2];
#pragma unroll
        for (int ci = 0; ci < 2; ++ci) {
            bh[ci] = *(const short8*)&Bhi_s[cur][wn + ci * 16 + ln][quad * 8];
            bl[ci] = *(const short8*)&Blo_s[cur][wn + ci * 16 + ln][quad * 8];
        }
        int kob = it * 4 + quad;
#pragma unroll
        for (int mi = 0; mi < MI; ++mi) {
            size_t aoff = ((size_t)((mtb + mi) * 64 + kob) * 16 + ln) * 8;
            short8 Ah = *(const short8*)(Ahi + aoff);
            short8 Al = *(const short8*)(Alo + aoff);
#pragma unroll
            for (int ci = 0; ci < 2; ++ci) {
                acc[mi][ci] = __builtin_amdgcn_mfma_f32_16x16x32_bf16(Ah, bh[ci], acc[mi][ci], 0, 0, 0);
                acc[mi][ci] = __builtin_amdgcn_mfma_f32_16x16x32_bf16(Ah, bl[ci], acc[mi][ci], 0, 0, 0);
                acc[mi][ci] = __builtin_amdgcn_mfma_f32_16x16x32_bf16(Al, bh[ci], acc[mi][ci], 0, 0, 0);
            }
        }
    }

#pragma unroll
    for (int mi = 0; mi < MI; ++mi) {
#pragma unroll
        for (int ci = 0; ci < 2; ++ci) {
            int mrow = bm + wm + mi * 16 + quad * 4;
            int col = c0 + wn + ci * 16 + ln;
#pragma unroll
            for (int r = 0; r < 4; ++r)
                Y[(size_t)(mrow + r) * 1024 + col] = packbf(acc[mi][ci][r]);
        }
    }
}

// ---------------------------------------------------------------------------
// MFMA lin core: wave computes 16 rows x 64 cols; A = P-format activations,
// B = pre-packed split weights (global, no LDS). 3-pass split-bf16.
// ---------------------------------------------------------------------------
__device__ __forceinline__ void lin_core(const LinA& a,
        const unsigned short* __restrict__ Bh, const unsigned short* __restrict__ Bl,
        int row0, int ln, int quad, floatx4 acc[4]) {
    for (int s = 0; s < a.nseg; ++s) {
        const unsigned* ap = a.seg[s] + (size_t)(row0 + ln) * 64 + quad * 8;
#pragma unroll
        for (int hh = 0; hh < 2; ++hh) {
            unsigned u[8];
            *(uint4*)&u[0] = *(const uint4*)(ap + hh * 32);
            *(uint4*)&u[4] = *(const uint4*)(ap + hh * 32 + 4);
            short8 Ah, Al;
#pragma unroll
            for (int j = 0; j < 8; ++j) {
                Ah[j] = (short)(u[j] & 0xffffu);
                Al[j] = (short)(u[j] >> 16);
            }
            int O = s * 8 + hh * 4 + quad;
#pragma unroll
            for (int ci = 0; ci < 4; ++ci) {
                size_t boff = ((size_t)(O * 4 + ci) * 16 + ln) * 8;
                short8 B1 = *(const short8*)(Bh + boff);
                short8 B2 = *(const short8*)(Bl + boff);
                acc[ci] = __builtin_amdgcn_mfma_f32_16x16x32_bf16(Ah, B1, acc[ci], 0, 0, 0);
                acc[ci] = __builtin_amdgcn_mfma_f32_16x16x32_bf16(Al, B1, acc[ci], 0, 0, 0);
                acc[ci] = __builtin_amdgcn_mfma_f32_16x16x32_bf16(Ah, B2, acc[ci], 0, 0, 0);
            }
        }
    }
}

__device__ __forceinline__ void lin_scalar(const LinA& a, const float* __restrict__ WO,
        int row0, int ln, int quad, floatx4 acc[4]) {
    for (int t = 0; t < a.nsx; ++t) {
        const float* wr = WO + (size_t)a.sxrow[t] * 64;
        const float* sv = a.sx[t] + row0 + quad * 4;
#pragma unroll
        for (int rr = 0; rr < 4; ++rr) {
            float v = sv[rr];
#pragma unroll
            for (int ci = 0; ci < 4; ++ci)
                acc[ci][rr] = fmaf(v, wr[ci * 16 + ln], acc[ci][rr]);
        }
    }
}

// r/z gates (MFMA): grid (128, 2). y==0: GP = pack(sigmoid(pre_r)*h); y==1: Z.
__global__ __launch_bounds__(256) void lin_rz_mfma(
    LinA a,
    const unsigned short* Wrh, const unsigned short* Wrl, const float* WrO, const float* br,
    const unsigned short* Wzh, const unsigned short* Wzl, const float* WzO, const float* bz,
    const float* __restrict__ h, unsigned* __restrict__ GP, float* __restrict__ Z) {
    int w = threadIdx.x >> 6, lane = threadIdx.x & 63;
    int ln = lane & 15, quad = lane >> 4;
    int row0 = blockIdx.x * 64 + w * 16;
    int gate = blockIdx.y;
    const unsigned short* Bh = gate ? Wzh : Wrh;
    const unsigned short* Bl = gate ? Wzl : Wrl;
    const float* WO = gate ? WzO : WrO;
    const float* bias = gate ? bz : br;
    floatx4 acc[4];
#pragma unroll
    for (int ci = 0; ci < 4; ++ci) acc[ci] = (floatx4)0.0f;
    lin_core(a, Bh, Bl, row0, ln, quad, acc);
    if (a.nsx) lin_scalar(a, WO, row0, ln, quad, acc);
#pragma unroll
    for (int ci = 0; ci < 4; ++ci) {
        int col = ci * 16 + ln;
        float bv = bias[col];
#pragma unroll
        for (int rr = 0; rr < 4; ++rr) {
            int row = row0 + quad * 4 + rr;
            size_t idx = (size_t)row * 64 + col;
            float sg = sigmoid_fast(acc[ci][rr] + bv);
            if (gate == 0) GP[idx] = packbf(sg * h[idx]);
            else Z[idx] = sg;
        }
    }
}

// n gate + GRU update (MFMA): writes h fp32 + hP; optional fused projection.
__global__ __launch_bounds__(256) void lin_n_mfma(
    LinA a, const unsigned short* Wnh, const unsigned short* Wnl,
    const float* WnO, const float* bn,
    const float* __restrict__ Zb, float* __restrict__ h, unsigned* __restrict__ hP,
    int doProj, const float* __restrict__ Wp, const float* __restrict__ bp,
    float* __restrict__ out, float* __restrict__ di, int t) {
    int w = threadIdx.x >> 6, lane = threadIdx.x & 63;
    int ln = lane & 15, quad = lane >> 4;
    int row0 = blockIdx.x * 64 + w * 16;
    floatx4 acc[4];
#pragma unroll
    for (int ci = 0; ci < 4; ++ci) acc[ci] = (floatx4)0.0f;
    lin_core(a, Wnh, Wnl, row0, ln, quad, acc);
    if (a.nsx) lin_scalar(a, WnO, row0, ln, quad, acc);
    float p[4] = {0.0f, 0.0f, 0.0f, 0.0f};
#pragma unroll
    for (int ci = 0; ci < 4; ++ci) {
        int col = ci * 16 + ln;
        float bv = bn[col];
        float wpv = doProj ? Wp[col] : 0.0f;
#pragma unroll
        for (int rr = 0; rr < 4; ++rr) {
            int row = row0 + quad * 4 + rr;
            size_t idx = (size_t)row * 64 + col;
            float nn = tanh_fast(acc[ci][rr] + bv);
            float z = Zb[idx];
            float hv = h[idx];
            float o = (1.0f - z) * hv + z * nn;
            h[idx] = o;
            hP[idx] = packbf(o);
            p[rr] = fmaf(o, wpv, p[rr]);
        }
    }
    if (doProj) {
#pragma unroll
        for (int rr = 0; rr < 4; ++rr) {
            p[rr] += __shfl_xor(p[rr], 1, 64);
            p[rr] += __shfl_xor(p[rr], 2, 64);
            p[rr] += __shfl_xor(p[rr], 4, 64);
            p[rr] += __shfl_xor(p[rr], 8, 64);
        }
        if (ln == 0) {
            float bpv = bp[0];
#pragma unroll
            for (int rr = 0; rr < 4; ++rr) {
                int row = row0 + quad * 4 + rr;
                float y = p[rr] + bpv;
                int n = row >> 4, b = row & 15;
                out[(b * T_OUT + t) * 512 + n] = y;
                di[row] = y;
            }
        }
    }
}

// ---------------------------------------------------------------------------
extern "C" void kernel_launch(void* const* d_in, const int* in_sizes, int n_in,
                              void* d_out, int out_size, void* d_ws, size_t ws_size,
                              hipStream_t stream) {
    (void)in_sizes; (void)n_in; (void)out_size; (void)ws_size;
    const float* x   = (const float*)d_in[0];
    const float* A   = (const float*)d_in[1];
    const float* Wr0 = (const float*)d_in[2];  const float* br0 = (const float*)d_in[3];
    const float* Wz0 = (const float*)d_in[4];  const float* bz0 = (const float*)d_in[5];
    const float* Wn0 = (const float*)d_in[6];  const float* bn0 = (const float*)d_in[7];
    const float* Wr1 = (const float*)d_in[8];  const float* br1 = (const float*)d_in[9];
    const float* Wz1 = (const float*)d_in[10]; const float* bz1 = (const float*)d_in[11];
    const float* Wn1 = (const float*)d_in[12]; const float* bn1 = (const float*)d_in[13];
    const float* Wp  = (const float*)d_in[14]; const float* bp  = (const float*)d_in[15];
    float* out = (float*)d_out;

    float* ws = (float*)d_ws;
    size_t off = 0;
    auto alloc = [&](size_t nf) { float* p = ws + off; off += nf; return p; };
    float* Wf  = alloc(262144); float* Wb  = alloc(262144);
    float* W2f = alloc(262144); float* W2b = alloc(262144);
    float* rs  = alloc(512);    float* cs  = alloc(512);
    float* xenc = alloc((size_t)T_IN * NB);
    unsigned short* Whi[4]; unsigned short* Wlo[4];
    for (int m = 0; m < 4; ++m) Whi[m] = (unsigned short*)alloc(131072);
    for (int m = 0; m < 4; ++m) Wlo[m] = (unsigned short*)alloc(131072);
    unsigned* HAall = (unsigned*)alloc(4 * 524288);           // hops of h0 (persists)
    unsigned* HA_P[4]; for (int m = 0; m < 4; ++m) HA_P[m] = HAall + (size_t)m * 524288;
    unsigned* HB_P[4]; unsigned* HG_P[4];
    for (int m = 0; m < 4; ++m) HB_P[m] = (unsigned*)alloc(524288);
    for (int m = 0; m < 4; ++m) HG_P[m] = (unsigned*)alloc(524288);
    unsigned* GP  = (unsigned*)alloc(524288);
    unsigned* h0P = (unsigned*)alloc(524288);
    unsigned* h1P = (unsigned*)alloc(524288);
    float* Z  = alloc(524288);
    float* h0 = alloc(524288);
    float* h1 = alloc(524288);
    float* XHE = alloc((size_t)T_IN * 4 * NB);                // encoder x-hops
    float* HXSdec = alloc(4 * NB);
    float* di = alloc(NB);
    unsigned short* LWh[6]; unsigned short* LWl[6];
    for (int g = 0; g < 3; ++g) { LWh[g] = (unsigned short*)alloc(10240); LWl[g] = (unsigned short*)alloc(10240); }
    for (int g = 3; g < 6; ++g) { LWh[g] = (unsigned short*)alloc(20480); LWl[g] = (unsigned short*)alloc(20480); }

    hipMemsetAsync(h0, 0, 524288 * sizeof(float), stream);
    hipMemsetAsync(h1, 0, 524288 * sizeof(float), stream);
    hipMemsetAsync(h0P, 0, 524288 * sizeof(unsigned), stream);
    hipMemsetAsync(h1P, 0, 524288 * sizeof(unsigned), stream);
    hipMemsetAsync(HAall, 0, 4ul * 524288 * sizeof(unsigned), stream);

    xenc_kernel<<<dim3((T_IN * NB) / 256), 256, 0, stream>>>(x, xenc);
    sums_kernel<<<dim3(512), 256, 0, stream>>>(A, rs, cs);
    fill_kernel<<<dim3(512), 256, 0, stream>>>(A, rs, cs, Wf, Wb);

    { // W2f = Wf@Wf, W2b = Wb@Wb (fp32, setup only)
        HopA w2 = {};
        w2.M[0] = Wf; w2.M[1] = Wb;
        w2.dst0[0] = W2f; w2.dst0[1] = W2b;
        ghop_kernel<<<dim3(8, 8, 2), 256, 0, stream>>>(w2);
    }
    { // pack hop A-operands
        WPack p;
        p.w[0] = Wf; p.w[1] = W2f; p.w[2] = Wb; p.w[3] = W2b;
        for (int m = 0; m < 4; ++m) { p.hi[m] = Whi[m]; p.lo[m] = Wlo[m]; }
        wpack_kernel<<<dim3(1024, 4), 256, 0, stream>>>(p);
    }
    { // pack lin weights
        const float* WG[6] = { Wr0, Wz0, Wn0, Wr1, Wz1, Wn1 };
        for (int g = 0; g < 6; ++g) {
            LPack p = {};
            p.W = WG[g]; p.hi = LWh[g]; p.lo = LWl[g];
            if (g < 3) { p.nseg = 5;  for (int s = 0; s < 5; ++s)  p.base[s] = 65 * s + 1; }
            else       { p.nseg = 10; for (int s = 0; s < 10; ++s) p.base[s] = 64 * s; }
            lpack_kernel<<<dim3((p.nseg * 4096 + 255) / 256), 256, 0, stream>>>(p);
        }
    }
    { // all encoder x-hops in one launch
        XHopAll xa;
        xa.M[0] = Wf; xa.M[1] = W2f; xa.M[2] = Wb; xa.M[3] = W2b;
        xa.xenc = xenc; xa.dst = XHE;
        xhop_all_kernel<<<dim3(32, 4, T_IN), 256, 0, stream>>>(xa);
    }

    auto hopcom = [&](HopM& a) {
        for (int m = 0; m < 4; ++m) { a.Ahi[m] = Whi[m]; a.Alo[m] = Wlo[m]; }
    };

    for (int t = 0; t < T_IN + T_OUT; ++t) {
        int dec = (t >= T_IN);
        int td = t - T_IN;
        const float* xcur; const float* hxs;
        if (!dec) { xcur = xenc + (size_t)t * NB; hxs = XHE + (size_t)t * 4 * NB; }
        else if (td == 0) { xcur = xenc + (size_t)(T_IN - 1) * NB; hxs = XHE + (size_t)(T_IN - 1) * 4 * NB; }
        else {
            xcur = di; hxs = HXSdec;
            XHopOne xo;
            xo.M[0] = Wf; xo.M[1] = W2f; xo.M[2] = Wb; xo.M[3] = W2b;
            xo.xv = di; xo.dst = HXSdec;
            xhop_one_kernel<<<dim3(32, 4), 256, 0, stream>>>(xo);
        }

        // ---- cell0: gates read HA = hops of h0 (from prev step's cell1 hop)
        LinA la = {};
        la.nseg = 5;
        la.seg[0] = h0P;
        for (int m = 0; m < 4; ++m) la.seg[1 + m] = HA_P[m];
        la.nsx = 5;
        la.sx[0] = xcur; la.sxrow[0] = 0;
        for (int m = 0; m < 4; ++m) { la.sx[1 + m] = hxs + (size_t)m * NB; la.sxrow[1 + m] = 65 * (m + 1); }
        lin_rz_mfma<<<dim3(128, 2), 256, 0, stream>>>(la, LWh[0], LWl[0], Wr0, br0,
                                                      LWh[1], LWl[1], Wz0, bz0, h0, GP, Z);
        { // hops of G (64-row tiles, 512 blocks)
            HopM a = {}; hopcom(a);
            a.src0 = GP; a.tiles0 = 16;
            for (int m = 0; m < 4; ++m) a.dst0[m] = HG_P[m];
            hop_mfma<2><<<dim3(16, 8, 4), 256, 0, stream>>>(a);
        }
        LinA lb = la;
        lb.seg[0] = GP;
        for (int m = 0; m < 4; ++m) lb.seg[1 + m] = HG_P[m];
        lin_n_mfma<<<dim3(128), 256, 0, stream>>>(lb, LWh[2], LWl[2], Wn0, bn0, Z, h0, h0P,
                                                  0, (const float*)nullptr, (const float*)nullptr,
                                                  (float*)nullptr, (float*)nullptr, 0);

        // ---- cell1: hop h0' -> HA (also serves next step's cell0), h1 -> HB
        {
            HopM a = {}; hopcom(a);
            a.src0 = h0P; a.tiles0 = 16;
            a.src1 = h1P;
            for (int m = 0; m < 4; ++m) { a.dst0[m] = HA_P[m]; a.dst1[m] = HB_P[m]; }
            hop_mfma<4><<<dim3(32, 4, 4), 256, 0, stream>>>(a);
        }
        LinA lc = {};
        lc.nseg = 10; lc.nsx = 0;
        lc.seg[0] = h0P; lc.seg[1] = h1P;
        for (int m = 0; m < 4; ++m) { lc.seg[2 + 2 * m] = HA_P[m]; lc.seg[3 + 2 * m] = HB_P[m]; }
        lin_rz_mfma<<<dim3(128, 2), 256, 0, stream>>>(lc, LWh[3], LWl[3], Wr1, br1,
                                                      LWh[4], LWl[4], Wz1, bz1, h1, GP, Z);
        {
            HopM a = {}; hopcom(a);
            a.src0 = GP; a.tiles0 = 16;
            for (int m = 0; m < 4; ++m) a.dst0[m] = HG_P[m];
            hop_mfma<2><<<dim3(16, 8, 4), 256, 0, stream>>>(a);
        }
        LinA ld = lc;
        ld.seg[1] = GP;
        for (int m = 0; m < 4; ++m) ld.seg[3 + 2 * m] = HG_P[m];
        lin_n_mfma<<<dim3(128), 256, 0, stream>>>(ld, LWh[5], LWl[5], Wn1, bn1, Z, h1, h1P,
                                                  dec, Wp, bp, out, di, td);
    }
}

// Round 7
// 3246.249 us; speedup vs baseline: 4.5625x; 1.2504x over previous
//
#include <hip/hip_runtime.h>
#include <math.h>

#define T_IN   12
#define T_OUT  12
#define NB     8192          /* 512 nodes x 16 batch, row id = n*16+b */
#define EPSV   1e-6f

typedef __attribute__((ext_vector_type(8))) short short8;
typedef __attribute__((ext_vector_type(4))) float floatx4;

// ---------------------------------------------------------------------------
// bf16 helpers. P-format: uint = (lo_bf16 << 16) | hi_bf16, value ~ hi + lo.
// ---------------------------------------------------------------------------
__device__ __forceinline__ unsigned short f2bf(float x) {     // RNE (setup packs)
    union { float f; unsigned u; } v; v.f = x;
    unsigned r = v.u + 0x7fffu + ((v.u >> 16) & 1u);
    return (unsigned short)(r >> 16);
}
__device__ __forceinline__ float bf2f(unsigned short h) {
    union { float f; unsigned u; } v; v.u = ((unsigned)h) << 16;
    return v.f;
}
__device__ __forceinline__ unsigned packbf(float v) {         // trunc split (hot path)
    unsigned u = __float_as_uint(v);
    unsigned hu = u & 0xffff0000u;
    float r = v - __uint_as_float(hu);
    unsigned ru = __float_as_uint(r);
    return (ru & 0xffff0000u) | (u >> 16);
}

__device__ __forceinline__ float sigmoid_fast(float x) {
    return 1.0f / (1.0f + __expf(-x));
}
__device__ __forceinline__ float tanh_fast(float x) {
    float e = __expf(2.0f * x);
    return 1.0f - 2.0f / (e + 1.0f);
}

// ---------------------------------------------------------------------------
// Descriptors
// ---------------------------------------------------------------------------
struct HopA {                    // fp32 setup GEMM (W^2 build)
    const float* M[4];
    float* dst0[4];
};

struct HopM {                    // MFMA hop: Y[z] = M[z] @ X, X/Y in P-format
    const unsigned short* Ahi[4]; const unsigned short* Alo[4];
    const unsigned* src0; const unsigned* src1;
    unsigned* dst0[4]; unsigned* dst1[4];
    int tiles0;
};

struct XHopAll { const float* M[4]; const float* xenc; float* dst; };  // 12 slices
struct XHopOne { const float* M[4]; const float* xv; float* dst; };

struct WPack { const float* w[4]; unsigned short* hi[4]; unsigned short* lo[4]; };

struct LPack {                   // lin-weight fragment pack
    const float* W; unsigned short* hi; unsigned short* lo;
    int base[10]; int nseg;
};

struct LinA {                    // lin GEMM input descriptor
    const unsigned* seg[10]; int nseg;        // P-format (8192 x 64) segments
    const float* sx[5]; int sxrow[5]; int nsx; // scalar (len-1) segments, fp32
};

// ---------------------------------------------------------------------------
// Setup kernels
// ---------------------------------------------------------------------------
__global__ void sums_kernel(const float* __restrict__ A, float* __restrict__ rs,
                            float* __restrict__ cs) {
    int i = blockIdx.x;
    int t = threadIdx.x;
    __shared__ float s1[256], s2[256];
    float a = A[i * 512 + t] + A[i * 512 + t + 256];
    float b = A[t * 512 + i] + A[(t + 256) * 512 + i];
    s1[t] = a; s2[t] = b;
    __syncthreads();
    for (int off = 128; off > 0; off >>= 1) {
        if (t < off) { s1[t] += s1[t + off]; s2[t] += s2[t + off]; }
        __syncthreads();
    }
    if (t == 0) { rs[i] = s1[0]; cs[i] = s2[0]; }
}

__global__ void fill_kernel(const float* __restrict__ A, const float* __restrict__ rs,
                            const float* __restrict__ cs, float* __restrict__ Wf,
                            float* __restrict__ Wb) {
    int i = blockIdx.x;
    float irs = 1.0f / (rs[i] + EPSV);
    float ics = 1.0f / (cs[i] + EPSV);
    for (int j = threadIdx.x; j < 512; j += 256) {
        Wf[i * 512 + j] = A[i * 512 + j] * irs;
        Wb[i * 512 + j] = A[j * 512 + i] * ics;
    }
}

__global__ void xenc_kernel(const float* __restrict__ x, float* __restrict__ xenc) {
    int idx = blockIdx.x * 256 + threadIdx.x;
    if (idx >= T_IN * NB) return;
    int j = idx & 511;
    int b = (idx >> 9) & 15;
    int t = idx >> 13;
    xenc[t * NB + j * 16 + b] = x[(b * T_IN + t) * 512 + j];
}

// fp32 GEMM for the setup-only W^2 = W @ W build. 64x64 tile, 4x4 micro.
__global__ __launch_bounds__(256) void ghop_kernel(HopA a) {
    int z = blockIdx.z;
    const float* Wm = a.M[z];
    const float* X = Wm;
    float* Y = a.dst0[z];
    int col0 = blockIdx.x * 64;
    int row0 = blockIdx.y * 64;
    int tid = threadIdx.x;
    int tx = tid & 15, ty = tid >> 4;
    int kkA = tid & 15, rrA = tid >> 4;
    int ccB = tid & 63, kkB = tid >> 6;

    __shared__ float As[16][68], Bs[16][68];
    float acc[4][4] = {};

    const float* wp = Wm + (row0 + rrA) * 512 + kkA;
    const float* xp = X + (size_t)(col0 + ccB) + (size_t)kkB * 512;

    float ra[4], rb[4];
#pragma unroll
    for (int p = 0; p < 4; ++p) ra[p] = wp[p * 16 * 512];
#pragma unroll
    for (int p = 0; p < 4; ++p) rb[p] = xp[(size_t)(p * 4) * 512];

    for (int k0 = 0; k0 < 512; k0 += 16) {
#pragma unroll
        for (int p = 0; p < 4; ++p) As[kkA][rrA + p * 16] = ra[p];
#pragma unroll
        for (int p = 0; p < 4; ++p) Bs[kkB + p * 4][ccB] = rb[p];
        __syncthreads();
        if (k0 + 16 < 512) {
            int kn = k0 + 16;
#pragma unroll
            for (int p = 0; p < 4; ++p) ra[p] = wp[p * 16 * 512 + kn];
#pragma unroll
            for (int p = 0; p < 4; ++p) rb[p] = xp[(size_t)(kn + p * 4) * 512];
        }
#pragma unroll
        for (int k = 0; k < 16; ++k) {
            const float4 a4 = *(const float4*)&As[k][ty * 4];
            const float4 b4 = *(const float4*)&Bs[k][tx * 4];
            float av[4] = { a4.x, a4.y, a4.z, a4.w };
            float bv[4] = { b4.x, b4.y, b4.z, b4.w };
#pragma unroll
            for (int i = 0; i < 4; ++i)
#pragma unroll
                for (int j = 0; j < 4; ++j)
                    acc[i][j] = fmaf(av[i], bv[j], acc[i][j]);
        }
        __syncthreads();
    }

    int colw = col0 + tx * 4;
#pragma unroll
    for (int i = 0; i < 4; ++i) {
        int row = row0 + ty * 4 + i;
        *(float4*)&Y[(size_t)row * 512 + colw] =
            make_float4(acc[i][0], acc[i][1], acc[i][2], acc[i][3]);
    }
}

// Pack W (512x512 fp32) into A-fragment-contiguous bf16 hi/lo (for hops)
__global__ void wpack_kernel(WPack a) {
    int z = blockIdx.y;
    int idx = blockIdx.x * 256 + threadIdx.x;   // 0..262143
    int m = idx >> 9, k = idx & 511;
    float x = a.w[z][idx];
    unsigned short h = f2bf(x);
    unsigned short l = f2bf(x - bf2f(h));
    int p = (((m >> 4) * 64 + (k >> 3)) * 16 + (m & 15)) * 8 + (k & 7);
    a.hi[z][p] = h;
    a.lo[z][p] = l;
}

// Pack lin weights (K x 64) into B-fragment order over len-64 segments.
__global__ void lpack_kernel(LPack p) {
    int idx = blockIdx.x * 256 + threadIdx.x;
    if (idx >= p.nseg * 4096) return;
    int j = idx & 7, ln = (idx >> 3) & 15, ntl = (idx >> 7) & 3, O = idx >> 9;
    int s = O >> 3, o8 = O & 7;
    int row = p.base[s] + o8 * 8 + j;
    int col = ntl * 16 + ln;
    float v = p.W[(size_t)row * 64 + col];
    unsigned short h = f2bf(v);
    p.hi[idx] = h;
    p.lo[idx] = f2bf(v - bf2f(h));
}

// All 12 encoder x-hop slices: dst[(t*4+m)*NB + node*16+b].  8 accumulators.
__global__ void xhop_all_kernel(XHopAll a) {
    int t = blockIdx.z, mz = blockIdx.y;
    int m = blockIdx.x * 16 + (threadIdx.x >> 4);
    int c = threadIdx.x & 15;
    const float* wrow = a.M[mz] + (size_t)m * 512;
    const float* xv = a.xenc + (size_t)t * NB;
    float s[8] = {};
    for (int k = 0; k < 512; k += 8) {
        float4 w0 = *(const float4*)&wrow[k];
        float4 w1 = *(const float4*)&wrow[k + 4];
        s[0] = fmaf(w0.x, xv[(k + 0) * 16 + c], s[0]);
        s[1] = fmaf(w0.y, xv[(k + 1) * 16 + c], s[1]);
        s[2] = fmaf(w0.z, xv[(k + 2) * 16 + c], s[2]);
        s[3] = fmaf(w0.w, xv[(k + 3) * 16 + c], s[3]);
        s[4] = fmaf(w1.x, xv[(k + 4) * 16 + c], s[4]);
        s[5] = fmaf(w1.y, xv[(k + 5) * 16 + c], s[5]);
        s[6] = fmaf(w1.z, xv[(k + 6) * 16 + c], s[6]);
        s[7] = fmaf(w1.w, xv[(k + 7) * 16 + c], s[7]);
    }
    float r = ((s[0] + s[1]) + (s[2] + s[3])) + ((s[4] + s[5]) + (s[6] + s[7]));
    a.dst[((size_t)t * 4 + mz) * NB + m * 16 + c] = r;
}

// Single decoder x-hop: dst[m*NB...] for 4 mats.  8 accumulators.
__global__ void xhop_one_kernel(XHopOne a) {
    int mz = blockIdx.y;
    int m = blockIdx.x * 16 + (threadIdx.x >> 4);
    int c = threadIdx.x & 15;
    const float* wrow = a.M[mz] + (size_t)m * 512;
    const float* xv = a.xv;
    float s[8] = {};
    for (int k = 0; k < 512; k += 8) {
        float4 w0 = *(const float4*)&wrow[k];
        float4 w1 = *(const float4*)&wrow[k + 4];
        s[0] = fmaf(w0.x, xv[(k + 0) * 16 + c], s[0]);
        s[1] = fmaf(w0.y, xv[(k + 1) * 16 + c], s[1]);
        s[2] = fmaf(w0.z, xv[(k + 2) * 16 + c], s[2]);
        s[3] = fmaf(w0.w, xv[(k + 3) * 16 + c], s[3]);
        s[4] = fmaf(w1.x, xv[(k + 4) * 16 + c], s[4]);
        s[5] = fmaf(w1.y, xv[(k + 5) * 16 + c], s[5]);
        s[6] = fmaf(w1.z, xv[(k + 6) * 16 + c], s[6]);
        s[7] = fmaf(w1.w, xv[(k + 7) * 16 + c], s[7]);
    }
    float r = ((s[0] + s[1]) + (s[2] + s[3])) + ((s[4] + s[5]) + (s[6] + s[7]));
    a.dst[(size_t)mz * NB + m * 16 + c] = r;
}

// ---------------------------------------------------------------------------
// MFMA hop GEMM: Y[z](512x1024) = M[z](512x512) @ X(512x1024); X,Y P-format.
// Split-bf16 3-pass. Block tile (MI*32)m x 64n x 32k, 4 waves as 2x2,
// wave tile (MI*16)m x 32n. Double-buffered LDS, ONE barrier per k-chunk.
// ---------------------------------------------------------------------------
template<int MI>
__global__ __launch_bounds__(256) void hop_mfma(HopM a) {
    int z = blockIdx.z;
    int nt = blockIdx.x;
    const unsigned* X; unsigned* Y; int c0;
    if (nt < a.tiles0) { X = a.src0; Y = a.dst0[z]; c0 = nt * 64; }
    else { X = a.src1; Y = a.dst1[z]; c0 = (nt - a.tiles0) * 64; }
    const unsigned short* Ahi = a.Ahi[z];
    const unsigned short* Alo = a.Alo[z];
    int bm = blockIdx.y * (MI * 32);

    __shared__ unsigned short Bhi_s[2][64][40];
    __shared__ unsigned short Blo_s[2][64][40];

    int tid = threadIdx.x;
    int lane = tid & 63, w = tid >> 6;
    int wm = (w & 1) * (MI * 16), wn = (w >> 1) * 32;
    int ln = lane & 15, quad = lane >> 4;
    int sc = tid & 63, skh = tid >> 6;

    floatx4 acc[MI][2];
#pragma unroll
    for (int mi = 0; mi < MI; ++mi)
#pragma unroll
        for (int ci = 0; ci < 2; ++ci) acc[mi][ci] = (floatx4)0.0f;

    const unsigned* xbase = X + c0 + sc;
    int mtb = (bm + wm) >> 4;

    unsigned uv[8];
    // chunk 0 -> buf 0 (no barrier needed before first loop barrier)
#pragma unroll
    for (int j = 0; j < 8; ++j)
        uv[j] = xbase[(size_t)(skh * 8 + j) * 1024];
    {
        short8 h8, l8;
#pragma unroll
        for (int j = 0; j < 8; ++j) {
            h8[j] = (short)(uv[j] & 0xffffu);
            l8[j] = (short)(uv[j] >> 16);
        }
        *(short8*)&Bhi_s[0][sc][skh * 8] = h8;
        *(short8*)&Blo_s[0][sc][skh * 8] = l8;
    }
    // chunk 1 -> regs
#pragma unroll
    for (int j = 0; j < 8; ++j)
        uv[j] = xbase[(size_t)(32 + skh * 8 + j) * 1024];

    for (int it = 0; it < 16; ++it) {
        __syncthreads();
        int cur = it & 1;
        if (it + 1 < 16) {                  // stage chunk it+1 into other buf
            short8 h8, l8;
#pragma unroll
            for (int j = 0; j < 8; ++j) {
                h8[j] = (short)(uv[j] & 0xffffu);
                l8[j] = (short)(uv[j] >> 16);
            }
            *(short8*)&Bhi_s[cur ^ 1][sc][skh * 8] = h8;
            *(short8*)&Blo_s[cur ^ 1][sc][skh * 8] = l8;
        }
        if (it + 2 < 16) {                  // prefetch chunk it+2
            int kn = (it + 2) * 32;
#pragma unroll
            for (int j = 0; j < 8; ++j)
                uv[j] = xbase[(size_t)(kn + skh * 8 + j) * 1024];
        }
        short8 bh[2], bl[2];
#pragma unroll
        for (int ci = 0; ci < 2; ++ci) {
            bh[ci] = *(const short8*)&Bhi_s[cur][wn + ci * 16 + ln][quad * 8];
            bl[ci] = *(const short8*)&Blo_s[cur][wn + ci * 16 + ln][quad * 8];
        }
        int kob = it * 4 + quad;
#pragma unroll
        for (int mi = 0; mi < MI; ++mi) {
            size_t aoff = ((size_t)((mtb + mi) * 64 + kob) * 16 + ln) * 8;
            short8 Ah = *(const short8*)(Ahi + aoff);
            short8 Al = *(const short8*)(Alo + aoff);
#pragma unroll
            for (int ci = 0; ci < 2; ++ci) {
                acc[mi][ci] = __builtin_amdgcn_mfma_f32_16x16x32_bf16(Ah, bh[ci], acc[mi][ci], 0, 0, 0);
                acc[mi][ci] = __builtin_amdgcn_mfma_f32_16x16x32_bf16(Ah, bl[ci], acc[mi][ci], 0, 0, 0);
                acc[mi][ci] = __builtin_amdgcn_mfma_f32_16x16x32_bf16(Al, bh[ci], acc[mi][ci], 0, 0, 0);
            }
        }
    }

#pragma unroll
    for (int mi = 0; mi < MI; ++mi) {
#pragma unroll
        for (int ci = 0; ci < 2; ++ci) {
            int mrow = bm + wm + mi * 16 + quad * 4;
            int col = c0 + wn + ci * 16 + ln;
#pragma unroll
            for (int r = 0; r < 4; ++r)
                Y[(size_t)(mrow + r) * 1024 + col] = packbf(acc[mi][ci][r]);
        }
    }
}

// ---------------------------------------------------------------------------
// MFMA lin core (ci-split): wave computes 16 rows x 32 cols (cihalf selects
// which 32).  A = P-format activations, B = pre-packed split weights.
// ---------------------------------------------------------------------------
__device__ __forceinline__ void lin_core2(const LinA& a,
        const unsigned short* __restrict__ Bh, const unsigned short* __restrict__ Bl,
        int row0, int ln, int quad, int cihalf, floatx4 acc[2]) {
    for (int s = 0; s < a.nseg; ++s) {
        const unsigned* ap = a.seg[s] + (size_t)(row0 + ln) * 64 + quad * 8;
#pragma unroll
        for (int hh = 0; hh < 2; ++hh) {
            unsigned u[8];
            *(uint4*)&u[0] = *(const uint4*)(ap + hh * 32);
            *(uint4*)&u[4] = *(const uint4*)(ap + hh * 32 + 4);
            short8 Ah, Al;
#pragma unroll
            for (int j = 0; j < 8; ++j) {
                Ah[j] = (short)(u[j] & 0xffffu);
                Al[j] = (short)(u[j] >> 16);
            }
            int O = s * 8 + hh * 4 + quad;
#pragma unroll
            for (int ci = 0; ci < 2; ++ci) {
                int c_abs = cihalf * 2 + ci;
                size_t boff = ((size_t)(O * 4 + c_abs) * 16 + ln) * 8;
                short8 B1 = *(const short8*)(Bh + boff);
                short8 B2 = *(const short8*)(Bl + boff);
                acc[ci] = __builtin_amdgcn_mfma_f32_16x16x32_bf16(Ah, B1, acc[ci], 0, 0, 0);
                acc[ci] = __builtin_amdgcn_mfma_f32_16x16x32_bf16(Al, B1, acc[ci], 0, 0, 0);
                acc[ci] = __builtin_amdgcn_mfma_f32_16x16x32_bf16(Ah, B2, acc[ci], 0, 0, 0);
            }
        }
    }
}

__device__ __forceinline__ void lin_scalar2(const LinA& a, const float* __restrict__ WO,
        int row0, int ln, int quad, int cihalf, floatx4 acc[2]) {
    for (int t = 0; t < a.nsx; ++t) {
        const float* wr = WO + (size_t)a.sxrow[t] * 64;
        const float* sv = a.sx[t] + row0 + quad * 4;
#pragma unroll
        for (int rr = 0; rr < 4; ++rr) {
            float v = sv[rr];
#pragma unroll
            for (int ci = 0; ci < 2; ++ci)
                acc[ci][rr] = fmaf(v, wr[(cihalf * 2 + ci) * 16 + ln], acc[ci][rr]);
        }
    }
}

// r/z gates: grid (128, 2 gates, 2 cihalf).  512 blocks.
__global__ __launch_bounds__(256) void lin_rz_mfma(
    LinA a,
    const unsigned short* Wrh, const unsigned short* Wrl, const float* WrO, const float* br,
    const unsigned short* Wzh, const unsigned short* Wzl, const float* WzO, const float* bz,
    const float* __restrict__ h, unsigned* __restrict__ GP, float* __restrict__ Z) {
    int w = threadIdx.x >> 6, lane = threadIdx.x & 63;
    int ln = lane & 15, quad = lane >> 4;
    int row0 = blockIdx.x * 64 + w * 16;
    int gate = blockIdx.y;
    int cihalf = blockIdx.z;
    const unsigned short* Bh = gate ? Wzh : Wrh;
    const unsigned short* Bl = gate ? Wzl : Wrl;
    const float* WO = gate ? WzO : WrO;
    const float* bias = gate ? bz : br;
    floatx4 acc[2];
    acc[0] = (floatx4)0.0f; acc[1] = (floatx4)0.0f;
    lin_core2(a, Bh, Bl, row0, ln, quad, cihalf, acc);
    if (a.nsx) lin_scalar2(a, WO, row0, ln, quad, cihalf, acc);
#pragma unroll
    for (int ci = 0; ci < 2; ++ci) {
        int col = (cihalf * 2 + ci) * 16 + ln;
        float bv = bias[col];
#pragma unroll
        for (int rr = 0; rr < 4; ++rr) {
            int row = row0 + quad * 4 + rr;
            size_t idx = (size_t)row * 64 + col;
            float sg = sigmoid_fast(acc[ci][rr] + bv);
            if (gate == 0) GP[idx] = packbf(sg * h[idx]);
            else Z[idx] = sg;
        }
    }
}

// n gate + GRU update: grid (256).  Block = 2 rowgrps x 2 cihalves (4 waves).
// Projection reduced across the two cihalf waves via LDS.
__global__ __launch_bounds__(256) void lin_n_mfma(
    LinA a, const unsigned short* Wnh, const unsigned short* Wnl,
    const float* WnO, const float* bn,
    const float* __restrict__ Zb, float* __restrict__ h, unsigned* __restrict__ hP,
    int doProj, const float* __restrict__ Wp, const float* __restrict__ bp,
    float* __restrict__ out, float* __restrict__ di, int t) {
    int w = threadIdx.x >> 6, lane = threadIdx.x & 63;
    int ln = lane & 15, quad = lane >> 4;
    int cihalf = w & 1, rsub = w >> 1;
    int row0 = (blockIdx.x * 2 + rsub) * 16;
    __shared__ float pr[2][2][16];
    floatx4 acc[2];
    acc[0] = (floatx4)0.0f; acc[1] = (floatx4)0.0f;
    lin_core2(a, Wnh, Wnl, row0, ln, quad, cihalf, acc);
    if (a.nsx) lin_scalar2(a, WnO, row0, ln, quad, cihalf, acc);
    float p[4] = {0.0f, 0.0f, 0.0f, 0.0f};
#pragma unroll
    for (int ci = 0; ci < 2; ++ci) {
        int col = (cihalf * 2 + ci) * 16 + ln;
        float bv = bn[col];
        float wpv = doProj ? Wp[col] : 0.0f;
#pragma unroll
        for (int rr = 0; rr < 4; ++rr) {
            int row = row0 + quad * 4 + rr;
            size_t idx = (size_t)row * 64 + col;
            float nn = tanh_fast(acc[ci][rr] + bv);
            float z = Zb[idx];
            float hv = h[idx];
            float o = (1.0f - z) * hv + z * nn;
            h[idx] = o;
            hP[idx] = packbf(o);
            p[rr] = fmaf(o, wpv, p[rr]);
        }
    }
    if (doProj) {
#pragma unroll
        for (int rr = 0; rr < 4; ++rr) {
            p[rr] += __shfl_xor(p[rr], 1, 64);
            p[rr] += __shfl_xor(p[rr], 2, 64);
            p[rr] += __shfl_xor(p[rr], 4, 64);
            p[rr] += __shfl_xor(p[rr], 8, 64);
        }
        if (ln == 0) {
#pragma unroll
            for (int rr = 0; rr < 4; ++rr)
                pr[cihalf][rsub][quad * 4 + rr] = p[rr];
        }
        __syncthreads();
        if (cihalf == 0 && ln == 0) {
            float bpv = bp[0];
#pragma unroll
            for (int rr = 0; rr < 4; ++rr) {
                int qr = quad * 4 + rr;
                int row = row0 + qr;
                float y = pr[0][rsub][qr] + pr[1][rsub][qr] + bpv;
                int n = row >> 4, b = row & 15;
                out[(b * T_OUT + t) * 512 + n] = y;
                di[row] = y;
            }
        }
    }
}

// ---------------------------------------------------------------------------
extern "C" void kernel_launch(void* const* d_in, const int* in_sizes, int n_in,
                              void* d_out, int out_size, void* d_ws, size_t ws_size,
                              hipStream_t stream) {
    (void)in_sizes; (void)n_in; (void)out_size; (void)ws_size;
    const float* x   = (const float*)d_in[0];
    const float* A   = (const float*)d_in[1];
    const float* Wr0 = (const float*)d_in[2];  const float* br0 = (const float*)d_in[3];
    const float* Wz0 = (const float*)d_in[4];  const float* bz0 = (const float*)d_in[5];
    const float* Wn0 = (const float*)d_in[6];  const float* bn0 = (const float*)d_in[7];
    const float* Wr1 = (const float*)d_in[8];  const float* br1 = (const float*)d_in[9];
    const float* Wz1 = (const float*)d_in[10]; const float* bz1 = (const float*)d_in[11];
    const float* Wn1 = (const float*)d_in[12]; const float* bn1 = (const float*)d_in[13];
    const float* Wp  = (const float*)d_in[14]; const float* bp  = (const float*)d_in[15];
    float* out = (float*)d_out;

    float* ws = (float*)d_ws;
    size_t off = 0;
    auto alloc = [&](size_t nf) { float* p = ws + off; off += nf; return p; };
    float* Wf  = alloc(262144); float* Wb  = alloc(262144);
    float* W2f = alloc(262144); float* W2b = alloc(262144);
    float* rs  = alloc(512);    float* cs  = alloc(512);
    float* xenc = alloc((size_t)T_IN * NB);
    unsigned short* Whi[4]; unsigned short* Wlo[4];
    for (int m = 0; m < 4; ++m) Whi[m] = (unsigned short*)alloc(131072);
    for (int m = 0; m < 4; ++m) Wlo[m] = (unsigned short*)alloc(131072);
    unsigned* HAall = (unsigned*)alloc(4 * 524288);           // hops of h0 (persists)
    unsigned* HA_P[4]; for (int m = 0; m < 4; ++m) HA_P[m] = HAall + (size_t)m * 524288;
    unsigned* HB_P[4]; unsigned* HG_P[4];
    for (int m = 0; m < 4; ++m) HB_P[m] = (unsigned*)alloc(524288);
    for (int m = 0; m < 4; ++m) HG_P[m] = (unsigned*)alloc(524288);
    unsigned* GP  = (unsigned*)alloc(524288);
    unsigned* h0P = (unsigned*)alloc(524288);
    unsigned* h1P = (unsigned*)alloc(524288);
    float* Z  = alloc(524288);
    float* h0 = alloc(524288);
    float* h1 = alloc(524288);
    float* XHE = alloc((size_t)T_IN * 4 * NB);                // encoder x-hops
    float* HXSdec = alloc(4 * NB);
    float* di = alloc(NB);
    unsigned short* LWh[6]; unsigned short* LWl[6];
    for (int g = 0; g < 3; ++g) { LWh[g] = (unsigned short*)alloc(10240); LWl[g] = (unsigned short*)alloc(10240); }
    for (int g = 3; g < 6; ++g) { LWh[g] = (unsigned short*)alloc(20480); LWl[g] = (unsigned short*)alloc(20480); }

    hipMemsetAsync(h0, 0, 524288 * sizeof(float), stream);
    hipMemsetAsync(h1, 0, 524288 * sizeof(float), stream);
    hipMemsetAsync(h0P, 0, 524288 * sizeof(unsigned), stream);
    hipMemsetAsync(h1P, 0, 524288 * sizeof(unsigned), stream);
    hipMemsetAsync(HAall, 0, 4ul * 524288 * sizeof(unsigned), stream);

    xenc_kernel<<<dim3((T_IN * NB) / 256), 256, 0, stream>>>(x, xenc);
    sums_kernel<<<dim3(512), 256, 0, stream>>>(A, rs, cs);
    fill_kernel<<<dim3(512), 256, 0, stream>>>(A, rs, cs, Wf, Wb);

    { // W2f = Wf@Wf, W2b = Wb@Wb (fp32, setup only)
        HopA w2 = {};
        w2.M[0] = Wf; w2.M[1] = Wb;
        w2.dst0[0] = W2f; w2.dst0[1] = W2b;
        ghop_kernel<<<dim3(8, 8, 2), 256, 0, stream>>>(w2);
    }
    { // pack hop A-operands
        WPack p;
        p.w[0] = Wf; p.w[1] = W2f; p.w[2] = Wb; p.w[3] = W2b;
        for (int m = 0; m < 4; ++m) { p.hi[m] = Whi[m]; p.lo[m] = Wlo[m]; }
        wpack_kernel<<<dim3(1024, 4), 256, 0, stream>>>(p);
    }
    { // pack lin weights
        const float* WG[6] = { Wr0, Wz0, Wn0, Wr1, Wz1, Wn1 };
        for (int g = 0; g < 6; ++g) {
            LPack p = {};
            p.W = WG[g]; p.hi = LWh[g]; p.lo = LWl[g];
            if (g < 3) { p.nseg = 5;  for (int s = 0; s < 5; ++s)  p.base[s] = 65 * s + 1; }
            else       { p.nseg = 10; for (int s = 0; s < 10; ++s) p.base[s] = 64 * s; }
            lpack_kernel<<<dim3((p.nseg * 4096 + 255) / 256), 256, 0, stream>>>(p);
        }
    }
    { // all encoder x-hops in one launch
        XHopAll xa;
        xa.M[0] = Wf; xa.M[1] = W2f; xa.M[2] = Wb; xa.M[3] = W2b;
        xa.xenc = xenc; xa.dst = XHE;
        xhop_all_kernel<<<dim3(32, 4, T_IN), 256, 0, stream>>>(xa);
    }

    auto hopcom = [&](HopM& a) {
        for (int m = 0; m < 4; ++m) { a.Ahi[m] = Whi[m]; a.Alo[m] = Wlo[m]; }
    };

    for (int t = 0; t < T_IN + T_OUT; ++t) {
        int dec = (t >= T_IN);
        int td = t - T_IN;
        const float* xcur; const float* hxs;
        if (!dec) { xcur = xenc + (size_t)t * NB; hxs = XHE + (size_t)t * 4 * NB; }
        else if (td == 0) { xcur = xenc + (size_t)(T_IN - 1) * NB; hxs = XHE + (size_t)(T_IN - 1) * 4 * NB; }
        else {
            xcur = di; hxs = HXSdec;
            XHopOne xo;
            xo.M[0] = Wf; xo.M[1] = W2f; xo.M[2] = Wb; xo.M[3] = W2b;
            xo.xv = di; xo.dst = HXSdec;
            xhop_one_kernel<<<dim3(32, 4), 256, 0, stream>>>(xo);
        }

        // ---- cell0: gates read HA = hops of h0 (from prev step's cell1 hop)
        LinA la = {};
        la.nseg = 5;
        la.seg[0] = h0P;
        for (int m = 0; m < 4; ++m) la.seg[1 + m] = HA_P[m];
        la.nsx = 5;
        la.sx[0] = xcur; la.sxrow[0] = 0;
        for (int m = 0; m < 4; ++m) { la.sx[1 + m] = hxs + (size_t)m * NB; la.sxrow[1 + m] = 65 * (m + 1); }
        lin_rz_mfma<<<dim3(128, 2, 2), 256, 0, stream>>>(la, LWh[0], LWl[0], Wr0, br0,
                                                         LWh[1], LWl[1], Wz0, bz0, h0, GP, Z);
        { // hops of G (64-row tiles, 512 blocks)
            HopM a = {}; hopcom(a);
            a.src0 = GP; a.tiles0 = 16;
            for (int m = 0; m < 4; ++m) a.dst0[m] = HG_P[m];
            hop_mfma<2><<<dim3(16, 8, 4), 256, 0, stream>>>(a);
        }
        LinA lb = la;
        lb.seg[0] = GP;
        for (int m = 0; m < 4; ++m) lb.seg[1 + m] = HG_P[m];
        lin_n_mfma<<<dim3(256), 256, 0, stream>>>(lb, LWh[2], LWl[2], Wn0, bn0, Z, h0, h0P,
                                                  0, (const float*)nullptr, (const float*)nullptr,
                                                  (float*)nullptr, (float*)nullptr, 0);

        // ---- cell1: hop h0' -> HA (also serves next step's cell0), h1 -> HB
        {
            HopM a = {}; hopcom(a);
            a.src0 = h0P; a.tiles0 = 16;
            a.src1 = h1P;
            for (int m = 0; m < 4; ++m) { a.dst0[m] = HA_P[m]; a.dst1[m] = HB_P[m]; }
            hop_mfma<4><<<dim3(32, 4, 4), 256, 0, stream>>>(a);
        }
        LinA lc = {};
        lc.nseg = 10; lc.nsx = 0;
        lc.seg[0] = h0P; lc.seg[1] = h1P;
        for (int m = 0; m < 4; ++m) { lc.seg[2 + 2 * m] = HA_P[m]; lc.seg[3 + 2 * m] = HB_P[m]; }
        lin_rz_mfma<<<dim3(128, 2, 2), 256, 0, stream>>>(lc, LWh[3], LWl[3], Wr1, br1,
                                                         LWh[4], LWl[4], Wz1, bz1, h1, GP, Z);
        {
            HopM a = {}; hopcom(a);
            a.src0 = GP; a.tiles0 = 16;
            for (int m = 0; m < 4; ++m) a.dst0[m] = HG_P[m];
            hop_mfma<2><<<dim3(16, 8, 4), 256, 0, stream>>>(a);
        }
        LinA ld = lc;
        ld.seg[1] = GP;
        for (int m = 0; m < 4; ++m) ld.seg[3 + 2 * m] = HG_P[m];
        lin_n_mfma<<<dim3(256), 256, 0, stream>>>(ld, LWh[5], LWl[5], Wn1, bn1, Z, h1, h1P,
                                                  dec, Wp, bp, out, di, td);
    }
}

// Round 8
// 2962.613 us; speedup vs baseline: 4.9994x; 1.0957x over previous
//
#include <hip/hip_runtime.h>
#include <math.h>

#define T_IN   12
#define T_OUT  12
#define NB     8192          /* 512 nodes x 16 batch, row id = n*16+b */
#define EPSV   1e-6f

typedef __attribute__((ext_vector_type(8))) short short8;
typedef __attribute__((ext_vector_type(4))) float floatx4;

// ---------------------------------------------------------------------------
// bf16 helpers. P-format: uint = (lo_bf16 << 16) | hi_bf16, value ~ hi + lo.
// ---------------------------------------------------------------------------
__device__ __forceinline__ unsigned short f2bf(float x) {     // RNE (setup packs)
    union { float f; unsigned u; } v; v.f = x;
    unsigned r = v.u + 0x7fffu + ((v.u >> 16) & 1u);
    return (unsigned short)(r >> 16);
}
__device__ __forceinline__ float bf2f(unsigned short h) {
    union { float f; unsigned u; } v; v.u = ((unsigned)h) << 16;
    return v.f;
}
__device__ __forceinline__ unsigned packbf(float v) {         // trunc split (hot path)
    unsigned u = __float_as_uint(v);
    unsigned hu = u & 0xffff0000u;
    float r = v - __uint_as_float(hu);
    unsigned ru = __float_as_uint(r);
    return (ru & 0xffff0000u) | (u >> 16);
}
__device__ __forceinline__ void split2(float v, short& h, short& l) {  // trunc split
    unsigned u = __float_as_uint(v);
    h = (short)(u >> 16);
    float r = v - __uint_as_float(u & 0xffff0000u);
    l = (short)(__float_as_uint(r) >> 16);
}

__device__ __forceinline__ float sigmoid_fast(float x) {
    return 1.0f / (1.0f + __expf(-x));
}
__device__ __forceinline__ float tanh_fast(float x) {
    float e = __expf(2.0f * x);
    return 1.0f - 2.0f / (e + 1.0f);
}

// ---------------------------------------------------------------------------
// Descriptors
// ---------------------------------------------------------------------------
struct HopA {                    // fp32 setup GEMM (W^2 build)
    const float* M[4];
    float* dst0[4];
};

struct HopM {                    // MFMA hop: Y[z] = M[z] @ X, X/Y in P-format
    const unsigned short* Ahi[4]; const unsigned short* Alo[4];
    const unsigned* src0; const unsigned* src1;
    unsigned* dst0[4]; unsigned* dst1[4];
    int tiles0;
};

struct XHopM {                   // MFMA x-hop: fp32 in/out
    const unsigned short* Ahi[4]; const unsigned short* Alo[4];
    const float* X;              // addr = (col>>4)*8192 + k*16 + (col&15)
    float* Y;                    // Y[((col>>4)*4+z)*NB + m*16 + (col&15)]
    int ncols;                   // 192 (encoder all-t) or 16 (decoder)
};

struct WPack { const float* w[4]; unsigned short* hi[4]; unsigned short* lo[4]; };

struct LPack {                   // lin-weight fragment pack
    const float* W; unsigned short* hi; unsigned short* lo;
    int base[10]; int nseg;
};

struct LinA {                    // lin GEMM input descriptor
    const unsigned* seg[10]; int nseg;        // P-format (8192 x 64) segments
    const float* sx[5]; int sxrow[5]; int nsx; // scalar (len-1) segments, fp32
};

// ---------------------------------------------------------------------------
// Setup kernels
// ---------------------------------------------------------------------------
__global__ void sums_kernel(const float* __restrict__ A, float* __restrict__ rs,
                            float* __restrict__ cs) {
    int i = blockIdx.x;
    int t = threadIdx.x;
    __shared__ float s1[256], s2[256];
    float a = A[i * 512 + t] + A[i * 512 + t + 256];
    float b = A[t * 512 + i] + A[(t + 256) * 512 + i];
    s1[t] = a; s2[t] = b;
    __syncthreads();
    for (int off = 128; off > 0; off >>= 1) {
        if (t < off) { s1[t] += s1[t + off]; s2[t] += s2[t + off]; }
        __syncthreads();
    }
    if (t == 0) { rs[i] = s1[0]; cs[i] = s2[0]; }
}

__global__ void fill_kernel(const float* __restrict__ A, const float* __restrict__ rs,
                            const float* __restrict__ cs, float* __restrict__ Wf,
                            float* __restrict__ Wb) {
    int i = blockIdx.x;
    float irs = 1.0f / (rs[i] + EPSV);
    float ics = 1.0f / (cs[i] + EPSV);
    for (int j = threadIdx.x; j < 512; j += 256) {
        Wf[i * 512 + j] = A[i * 512 + j] * irs;
        Wb[i * 512 + j] = A[j * 512 + i] * ics;
    }
}

__global__ void xenc_kernel(const float* __restrict__ x, float* __restrict__ xenc) {
    int idx = blockIdx.x * 256 + threadIdx.x;
    if (idx >= T_IN * NB) return;
    int j = idx & 511;
    int b = (idx >> 9) & 15;
    int t = idx >> 13;
    xenc[t * NB + j * 16 + b] = x[(b * T_IN + t) * 512 + j];
}

// fp32 GEMM for the setup-only W^2 = W @ W build. 64x64 tile, 4x4 micro.
__global__ __launch_bounds__(256) void ghop_kernel(HopA a) {
    int z = blockIdx.z;
    const float* Wm = a.M[z];
    const float* X = Wm;
    float* Y = a.dst0[z];
    int col0 = blockIdx.x * 64;
    int row0 = blockIdx.y * 64;
    int tid = threadIdx.x;
    int tx = tid & 15, ty = tid >> 4;
    int kkA = tid & 15, rrA = tid >> 4;
    int ccB = tid & 63, kkB = tid >> 6;

    __shared__ float As[16][68], Bs[16][68];
    float acc[4][4] = {};

    const float* wp = Wm + (row0 + rrA) * 512 + kkA;
    const float* xp = X + (size_t)(col0 + ccB) + (size_t)kkB * 512;

    float ra[4], rb[4];
#pragma unroll
    for (int p = 0; p < 4; ++p) ra[p] = wp[p * 16 * 512];
#pragma unroll
    for (int p = 0; p < 4; ++p) rb[p] = xp[(size_t)(p * 4) * 512];

    for (int k0 = 0; k0 < 512; k0 += 16) {
#pragma unroll
        for (int p = 0; p < 4; ++p) As[kkA][rrA + p * 16] = ra[p];
#pragma unroll
        for (int p = 0; p < 4; ++p) Bs[kkB + p * 4][ccB] = rb[p];
        __syncthreads();
        if (k0 + 16 < 512) {
            int kn = k0 + 16;
#pragma unroll
            for (int p = 0; p < 4; ++p) ra[p] = wp[p * 16 * 512 + kn];
#pragma unroll
            for (int p = 0; p < 4; ++p) rb[p] = xp[(size_t)(kn + p * 4) * 512];
        }
#pragma unroll
        for (int k = 0; k < 16; ++k) {
            const float4 a4 = *(const float4*)&As[k][ty * 4];
            const float4 b4 = *(const float4*)&Bs[k][tx * 4];
            float av[4] = { a4.x, a4.y, a4.z, a4.w };
            float bv[4] = { b4.x, b4.y, b4.z, b4.w };
#pragma unroll
            for (int i = 0; i < 4; ++i)
#pragma unroll
                for (int j = 0; j < 4; ++j)
                    acc[i][j] = fmaf(av[i], bv[j], acc[i][j]);
        }
        __syncthreads();
    }

    int colw = col0 + tx * 4;
#pragma unroll
    for (int i = 0; i < 4; ++i) {
        int row = row0 + ty * 4 + i;
        *(float4*)&Y[(size_t)row * 512 + colw] =
            make_float4(acc[i][0], acc[i][1], acc[i][2], acc[i][3]);
    }
}

// Pack W (512x512 fp32) into A-fragment-contiguous bf16 hi/lo (for hops)
__global__ void wpack_kernel(WPack a) {
    int z = blockIdx.y;
    int idx = blockIdx.x * 256 + threadIdx.x;   // 0..262143
    int m = idx >> 9, k = idx & 511;
    float x = a.w[z][idx];
    unsigned short h = f2bf(x);
    unsigned short l = f2bf(x - bf2f(h));
    int p = (((m >> 4) * 64 + (k >> 3)) * 16 + (m & 15)) * 8 + (k & 7);
    a.hi[z][p] = h;
    a.lo[z][p] = l;
}

// Pack lin weights (K x 64) into B-fragment order over len-64 segments.
__global__ void lpack_kernel(LPack p) {
    int idx = blockIdx.x * 256 + threadIdx.x;
    if (idx >= p.nseg * 4096) return;
    int j = idx & 7, ln = (idx >> 3) & 15, ntl = (idx >> 7) & 3, O = idx >> 9;
    int s = O >> 3, o8 = O & 7;
    int row = p.base[s] + o8 * 8 + j;
    int col = ntl * 16 + ln;
    float v = p.W[(size_t)row * 64 + col];
    unsigned short h = f2bf(v);
    p.hi[idx] = h;
    p.lo[idx] = f2bf(v - bf2f(h));
}

// ---------------------------------------------------------------------------
// MFMA hop GEMM: Y[z](512x1024) = M[z](512x512) @ X(512x1024); X,Y P-format.
// Split-bf16 3-pass. Block tile (MI*32)m x 64n x 32k, 4 waves as 2x2,
// wave tile (MI*16)m x 32n. Double-buffered LDS, ONE barrier per k-chunk.
// ---------------------------------------------------------------------------
template<int MI>
__global__ __launch_bounds__(256) void hop_mfma(HopM a) {
    int z = blockIdx.z;
    int nt = blockIdx.x;
    const unsigned* X; unsigned* Y; int c0;
    if (nt < a.tiles0) { X = a.src0; Y = a.dst0[z]; c0 = nt * 64; }
    else { X = a.src1; Y = a.dst1[z]; c0 = (nt - a.tiles0) * 64; }
    const unsigned short* Ahi = a.Ahi[z];
    const unsigned short* Alo = a.Alo[z];
    int bm = blockIdx.y * (MI * 32);

    __shared__ unsigned short Bhi_s[2][64][40];
    __shared__ unsigned short Blo_s[2][64][40];

    int tid = threadIdx.x;
    int lane = tid & 63, w = tid >> 6;
    int wm = (w & 1) * (MI * 16), wn = (w >> 1) * 32;
    int ln = lane & 15, quad = lane >> 4;
    int sc = tid & 63, skh = tid >> 6;

    floatx4 acc[MI][2];
#pragma unroll
    for (int mi = 0; mi < MI; ++mi)
#pragma unroll
        for (int ci = 0; ci < 2; ++ci) acc[mi][ci] = (floatx4)0.0f;

    const unsigned* xbase = X + c0 + sc;
    int mtb = (bm + wm) >> 4;

    unsigned uv[8];
#pragma unroll
    for (int j = 0; j < 8; ++j)
        uv[j] = xbase[(size_t)(skh * 8 + j) * 1024];
    {
        short8 h8, l8;
#pragma unroll
        for (int j = 0; j < 8; ++j) {
            h8[j] = (short)(uv[j] & 0xffffu);
            l8[j] = (short)(uv[j] >> 16);
        }
        *(short8*)&Bhi_s[0][sc][skh * 8] = h8;
        *(short8*)&Blo_s[0][sc][skh * 8] = l8;
    }
#pragma unroll
    for (int j = 0; j < 8; ++j)
        uv[j] = xbase[(size_t)(32 + skh * 8 + j) * 1024];

    for (int it = 0; it < 16; ++it) {
        __syncthreads();
        int cur = it & 1;
        if (it + 1 < 16) {
            short8 h8, l8;
#pragma unroll
            for (int j = 0; j < 8; ++j) {
                h8[j] = (short)(uv[j] & 0xffffu);
                l8[j] = (short)(uv[j] >> 16);
            }
            *(short8*)&Bhi_s[cur ^ 1][sc][skh * 8] = h8;
            *(short8*)&Blo_s[cur ^ 1][sc][skh * 8] = l8;
        }
        if (it + 2 < 16) {
            int kn = (it + 2) * 32;
#pragma unroll
            for (int j = 0; j < 8; ++j)
                uv[j] = xbase[(size_t)(kn + skh * 8 + j) * 1024];
        }
        short8 bh[2], bl[2];
#pragma unroll
        for (int ci = 0; ci < 2; ++ci) {
            bh[ci] = *(const short8*)&Bhi_s[cur][wn + ci * 16 + ln][quad * 8];
            bl[ci] = *(const short8*)&Blo_s[cur][wn + ci * 16 + ln][quad * 8];
        }
        int kob = it * 4 + quad;
#pragma unroll
        for (int mi = 0; mi < MI; ++mi) {
            size_t aoff = ((size_t)((mtb + mi) * 64 + kob) * 16 + ln) * 8;
            short8 Ah = *(const short8*)(Ahi + aoff);
            short8 Al = *(const short8*)(Alo + aoff);
#pragma unroll
            for (int ci = 0; ci < 2; ++ci) {
                acc[mi][ci] = __builtin_amdgcn_mfma_f32_16x16x32_bf16(Ah, bh[ci], acc[mi][ci], 0, 0, 0);
                acc[mi][ci] = __builtin_amdgcn_mfma_f32_16x16x32_bf16(Ah, bl[ci], acc[mi][ci], 0, 0, 0);
                acc[mi][ci] = __builtin_amdgcn_mfma_f32_16x16x32_bf16(Al, bh[ci], acc[mi][ci], 0, 0, 0);
            }
        }
    }

#pragma unroll
    for (int mi = 0; mi < MI; ++mi) {
#pragma unroll
        for (int ci = 0; ci < 2; ++ci) {
            int mrow = bm + wm + mi * 16 + quad * 4;
            int col = c0 + wn + ci * 16 + ln;
#pragma unroll
            for (int r = 0; r < 4; ++r)
                Y[(size_t)(mrow + r) * 1024 + col] = packbf(acc[mi][ci][r]);
        }
    }
}

// ---------------------------------------------------------------------------
// MFMA x-hop: Y[z] = M[z] @ X, X fp32 (col = t*16+b mapping), Y fp32.
// Block 64m x 64n, MI=2 wave layout, same dbuf staging with in-reg split.
// ---------------------------------------------------------------------------
__global__ __launch_bounds__(256) void xhop_mfma(XHopM a) {
    int z = blockIdx.z;
    int c0 = blockIdx.x * 64;
    const unsigned short* Ahi = a.Ahi[z];
    const unsigned short* Alo = a.Alo[z];
    int bm = blockIdx.y * 64;

    __shared__ unsigned short Bhi_s[2][64][40];
    __shared__ unsigned short Blo_s[2][64][40];

    int tid = threadIdx.x;
    int lane = tid & 63, w = tid >> 6;
    int wm = (w & 1) * 32, wn = (w >> 1) * 32;
    int ln = lane & 15, quad = lane >> 4;
    int sc = tid & 63, skh = tid >> 6;

    floatx4 acc[2][2];
#pragma unroll
    for (int mi = 0; mi < 2; ++mi)
#pragma unroll
        for (int ci = 0; ci < 2; ++ci) acc[mi][ci] = (floatx4)0.0f;

    int colS = c0 + sc;
    bool ok = colS < a.ncols;
    const float* xb = a.X + (size_t)(colS >> 4) * NB + (colS & 15);
    int mtb = (bm + wm) >> 4;

    float xv[8];
#pragma unroll
    for (int j = 0; j < 8; ++j)
        xv[j] = ok ? xb[(size_t)(skh * 8 + j) * 16] : 0.0f;
    {
        short8 h8, l8;
#pragma unroll
        for (int j = 0; j < 8; ++j) { short h, l; split2(xv[j], h, l); h8[j] = h; l8[j] = l; }
        *(short8*)&Bhi_s[0][sc][skh * 8] = h8;
        *(short8*)&Blo_s[0][sc][skh * 8] = l8;
    }
#pragma unroll
    for (int j = 0; j < 8; ++j)
        xv[j] = ok ? xb[(size_t)(32 + skh * 8 + j) * 16] : 0.0f;

    for (int it = 0; it < 16; ++it) {
        __syncthreads();
        int cur = it & 1;
        if (it + 1 < 16) {
            short8 h8, l8;
#pragma unroll
            for (int j = 0; j < 8; ++j) { short h, l; split2(xv[j], h, l); h8[j] = h; l8[j] = l; }
            *(short8*)&Bhi_s[cur ^ 1][sc][skh * 8] = h8;
            *(short8*)&Blo_s[cur ^ 1][sc][skh * 8] = l8;
        }
        if (it + 2 < 16) {
            int kn = (it + 2) * 32;
#pragma unroll
            for (int j = 0; j < 8; ++j)
                xv[j] = ok ? xb[(size_t)(kn + skh * 8 + j) * 16] : 0.0f;
        }
        short8 bh[2], bl[2];
#pragma unroll
        for (int ci = 0; ci < 2; ++ci) {
            bh[ci] = *(const short8*)&Bhi_s[cur][wn + ci * 16 + ln][quad * 8];
            bl[ci] = *(const short8*)&Blo_s[cur][wn + ci * 16 + ln][quad * 8];
        }
        int kob = it * 4 + quad;
#pragma unroll
        for (int mi = 0; mi < 2; ++mi) {
            size_t aoff = ((size_t)((mtb + mi) * 64 + kob) * 16 + ln) * 8;
            short8 Ah = *(const short8*)(Ahi + aoff);
            short8 Al = *(const short8*)(Alo + aoff);
#pragma unroll
            for (int ci = 0; ci < 2; ++ci) {
                acc[mi][ci] = __builtin_amdgcn_mfma_f32_16x16x32_bf16(Ah, bh[ci], acc[mi][ci], 0, 0, 0);
                acc[mi][ci] = __builtin_amdgcn_mfma_f32_16x16x32_bf16(Ah, bl[ci], acc[mi][ci], 0, 0, 0);
                acc[mi][ci] = __builtin_amdgcn_mfma_f32_16x16x32_bf16(Al, bh[ci], acc[mi][ci], 0, 0, 0);
            }
        }
    }

#pragma unroll
    for (int mi = 0; mi < 2; ++mi) {
#pragma unroll
        for (int ci = 0; ci < 2; ++ci) {
            int col = c0 + wn + ci * 16 + ln;
            if (col < a.ncols) {
                int mrow = bm + wm + mi * 16 + quad * 4;
                float* yb = a.Y + (size_t)((col >> 4) * 4 + z) * NB + (col & 15);
#pragma unroll
                for (int r = 0; r < 4; ++r)
                    yb[(size_t)(mrow + r) * 16] = acc[mi][ci][r];
            }
        }
    }
}

// ---------------------------------------------------------------------------
// MFMA lin core (ci-split, seg-range): wave computes 16 rows x 32 cols.
// ---------------------------------------------------------------------------
__device__ __forceinline__ void lin_core2(const unsigned* const* segs, int nseg, int s0,
        const unsigned short* __restrict__ Bh, const unsigned short* __restrict__ Bl,
        int row0, int ln, int quad, int cihalf, floatx4 acc[2]) {
    for (int s = 0; s < nseg; ++s) {
        const unsigned* ap = segs[s] + (size_t)(row0 + ln) * 64 + quad * 8;
#pragma unroll
        for (int hh = 0; hh < 2; ++hh) {
            unsigned u[8];
            *(uint4*)&u[0] = *(const uint4*)(ap + hh * 32);
            *(uint4*)&u[4] = *(const uint4*)(ap + hh * 32 + 4);
            short8 Ah, Al;
#pragma unroll
            for (int j = 0; j < 8; ++j) {
                Ah[j] = (short)(u[j] & 0xffffu);
                Al[j] = (short)(u[j] >> 16);
            }
            int O = (s0 + s) * 8 + hh * 4 + quad;
#pragma unroll
            for (int ci = 0; ci < 2; ++ci) {
                int c_abs = cihalf * 2 + ci;
                size_t boff = ((size_t)(O * 4 + c_abs) * 16 + ln) * 8;
                short8 B1 = *(const short8*)(Bh + boff);
                short8 B2 = *(const short8*)(Bl + boff);
                acc[ci] = __builtin_amdgcn_mfma_f32_16x16x32_bf16(Ah, B1, acc[ci], 0, 0, 0);
                acc[ci] = __builtin_amdgcn_mfma_f32_16x16x32_bf16(Al, B1, acc[ci], 0, 0, 0);
                acc[ci] = __builtin_amdgcn_mfma_f32_16x16x32_bf16(Ah, B2, acc[ci], 0, 0, 0);
            }
        }
    }
}

__device__ __forceinline__ void lin_scalar2(const LinA& a, const float* __restrict__ WO,
        int row0, int ln, int quad, int cihalf, floatx4 acc[2]) {
    for (int t = 0; t < a.nsx; ++t) {
        const float* wr = WO + (size_t)a.sxrow[t] * 64;
        const float* sv = a.sx[t] + row0 + quad * 4;
#pragma unroll
        for (int rr = 0; rr < 4; ++rr) {
            float v = sv[rr];
#pragma unroll
            for (int ci = 0; ci < 2; ++ci)
                acc[ci][rr] = fmaf(v, wr[(cihalf * 2 + ci) * 16 + ln], acc[ci][rr]);
        }
    }
}

// r/z gates: grid (128, 2 gates, 2 cihalf).  512 blocks.
__global__ __launch_bounds__(256) void lin_rz_mfma(
    LinA a,
    const unsigned short* Wrh, const unsigned short* Wrl, const float* WrO, const float* br,
    const unsigned short* Wzh, const unsigned short* Wzl, const float* WzO, const float* bz,
    const float* __restrict__ h, unsigned* __restrict__ GP, float* __restrict__ Z) {
    int w = threadIdx.x >> 6, lane = threadIdx.x & 63;
    int ln = lane & 15, quad = lane >> 4;
    int row0 = blockIdx.x * 64 + w * 16;
    int gate = blockIdx.y;
    int cihalf = blockIdx.z;
    const unsigned short* Bh = gate ? Wzh : Wrh;
    const unsigned short* Bl = gate ? Wzl : Wrl;
    const float* WO = gate ? WzO : WrO;
    const float* bias = gate ? bz : br;
    floatx4 acc[2];
    acc[0] = (floatx4)0.0f; acc[1] = (floatx4)0.0f;
    lin_core2(a.seg, a.nseg, 0, Bh, Bl, row0, ln, quad, cihalf, acc);
    if (a.nsx) lin_scalar2(a, WO, row0, ln, quad, cihalf, acc);
#pragma unroll
    for (int ci = 0; ci < 2; ++ci) {
        int col = (cihalf * 2 + ci) * 16 + ln;
        float bv = bias[col];
#pragma unroll
        for (int rr = 0; rr < 4; ++rr) {
            int row = row0 + quad * 4 + rr;
            size_t idx = (size_t)row * 64 + col;
            float sg = sigmoid_fast(acc[ci][rr] + bv);
            if (gate == 0) GP[idx] = packbf(sg * h[idx]);
            else Z[idx] = sg;
        }
    }
}

// n gate + GRU update.  Grid 512 blocks; block = 2 kh x 2 cihalf waves over
// one 16-row group.  K split across kh, partials combined via LDS.
__global__ __launch_bounds__(256) void lin_n_mfma(
    LinA a, int ksplit,
    const unsigned short* Wnh, const unsigned short* Wnl,
    const float* WnO, const float* bn,
    const float* __restrict__ Zb, float* __restrict__ h, unsigned* __restrict__ hP,
    int doProj, const float* __restrict__ Wp, const float* __restrict__ bp,
    float* __restrict__ out, float* __restrict__ di, int t) {
    int w = threadIdx.x >> 6, lane = threadIdx.x & 63;
    int ln = lane & 15, quad = lane >> 4;
    int kh = w & 1, cihalf = w >> 1;
    int row0 = blockIdx.x * 16;
    __shared__ float part[2][2][16][17];
    __shared__ float pr[2][16];
    floatx4 acc[2];
    acc[0] = (floatx4)0.0f; acc[1] = (floatx4)0.0f;
    if (kh == 0) {
        lin_core2(a.seg, ksplit, 0, Wnh, Wnl, row0, ln, quad, cihalf, acc);
    } else {
        lin_core2(a.seg + ksplit, a.nseg - ksplit, ksplit, Wnh, Wnl, row0, ln, quad, cihalf, acc);
        if (a.nsx) lin_scalar2(a, WnO, row0, ln, quad, cihalf, acc);
#pragma unroll
        for (int ci = 0; ci < 2; ++ci)
#pragma unroll
            for (int rr = 0; rr < 4; ++rr)
                part[cihalf][ci][quad * 4 + rr][ln] = acc[ci][rr];
    }
    __syncthreads();
    float p[4] = {0.0f, 0.0f, 0.0f, 0.0f};
    if (kh == 0) {
#pragma unroll
        for (int ci = 0; ci < 2; ++ci) {
            int col = (cihalf * 2 + ci) * 16 + ln;
            float bv = bn[col];
            float wpv = doProj ? Wp[col] : 0.0f;
#pragma unroll
            for (int rr = 0; rr < 4; ++rr) {
                int row = row0 + quad * 4 + rr;
                size_t idx = (size_t)row * 64 + col;
                float pre = acc[ci][rr] + part[cihalf][ci][quad * 4 + rr][ln] + bv;
                float nn = tanh_fast(pre);
                float z = Zb[idx];
                float hv = h[idx];
                float o = (1.0f - z) * hv + z * nn;
                h[idx] = o;
                hP[idx] = packbf(o);
                p[rr] = fmaf(o, wpv, p[rr]);
            }
        }
        if (doProj) {
#pragma unroll
            for (int rr = 0; rr < 4; ++rr) {
                p[rr] += __shfl_xor(p[rr], 1, 64);
                p[rr] += __shfl_xor(p[rr], 2, 64);
                p[rr] += __shfl_xor(p[rr], 4, 64);
                p[rr] += __shfl_xor(p[rr], 8, 64);
            }
            if (ln == 0) {
#pragma unroll
                for (int rr = 0; rr < 4; ++rr)
                    pr[cihalf][quad * 4 + rr] = p[rr];
            }
        }
    }
    __syncthreads();
    if (doProj && kh == 0 && cihalf == 0 && ln == 0) {
        float bpv = bp[0];
#pragma unroll
        for (int rr = 0; rr < 4; ++rr) {
            int qr = quad * 4 + rr;
            int row = row0 + qr;
            float y = pr[0][qr] + pr[1][qr] + bpv;
            int n = row >> 4, b = row & 15;
            out[(b * T_OUT + t) * 512 + n] = y;
            di[row] = y;
        }
    }
}

// ---------------------------------------------------------------------------
extern "C" void kernel_launch(void* const* d_in, const int* in_sizes, int n_in,
                              void* d_out, int out_size, void* d_ws, size_t ws_size,
                              hipStream_t stream) {
    (void)in_sizes; (void)n_in; (void)out_size; (void)ws_size;
    const float* x   = (const float*)d_in[0];
    const float* A   = (const float*)d_in[1];
    const float* Wr0 = (const float*)d_in[2];  const float* br0 = (const float*)d_in[3];
    const float* Wz0 = (const float*)d_in[4];  const float* bz0 = (const float*)d_in[5];
    const float* Wn0 = (const float*)d_in[6];  const float* bn0 = (const float*)d_in[7];
    const float* Wr1 = (const float*)d_in[8];  const float* br1 = (const float*)d_in[9];
    const float* Wz1 = (const float*)d_in[10]; const float* bz1 = (const float*)d_in[11];
    const float* Wn1 = (const float*)d_in[12]; const float* bn1 = (const float*)d_in[13];
    const float* Wp  = (const float*)d_in[14]; const float* bp  = (const float*)d_in[15];
    float* out = (float*)d_out;

    float* ws = (float*)d_ws;
    size_t off = 0;
    auto alloc = [&](size_t nf) { float* p = ws + off; off += nf; return p; };
    float* Wf  = alloc(262144); float* Wb  = alloc(262144);
    float* W2f = alloc(262144); float* W2b = alloc(262144);
    float* rs  = alloc(512);    float* cs  = alloc(512);
    float* xenc = alloc((size_t)T_IN * NB);
    unsigned short* Whi[4]; unsigned short* Wlo[4];
    for (int m = 0; m < 4; ++m) Whi[m] = (unsigned short*)alloc(131072);
    for (int m = 0; m < 4; ++m) Wlo[m] = (unsigned short*)alloc(131072);
    unsigned* HAall = (unsigned*)alloc(4 * 524288);           // hops of h0 (persists)
    unsigned* HA_P[4]; for (int m = 0; m < 4; ++m) HA_P[m] = HAall + (size_t)m * 524288;
    unsigned* HB_P[4]; unsigned* HG_P[4];
    for (int m = 0; m < 4; ++m) HB_P[m] = (unsigned*)alloc(524288);
    for (int m = 0; m < 4; ++m) HG_P[m] = (unsigned*)alloc(524288);
    unsigned* GP  = (unsigned*)alloc(524288);
    unsigned* h0P = (unsigned*)alloc(524288);
    unsigned* h1P = (unsigned*)alloc(524288);
    float* Z  = alloc(524288);
    float* h0 = alloc(524288);
    float* h1 = alloc(524288);
    float* XHE = alloc((size_t)T_IN * 4 * NB);                // encoder x-hops
    float* HXSdec = alloc(4 * NB);
    float* di = alloc(NB);
    unsigned short* LWh[6]; unsigned short* LWl[6];
    for (int g = 0; g < 3; ++g) { LWh[g] = (unsigned short*)alloc(10240); LWl[g] = (unsigned short*)alloc(10240); }
    for (int g = 3; g < 6; ++g) { LWh[g] = (unsigned short*)alloc(20480); LWl[g] = (unsigned short*)alloc(20480); }

    hipMemsetAsync(h0, 0, 524288 * sizeof(float), stream);
    hipMemsetAsync(h1, 0, 524288 * sizeof(float), stream);
    hipMemsetAsync(h0P, 0, 524288 * sizeof(unsigned), stream);
    hipMemsetAsync(h1P, 0, 524288 * sizeof(unsigned), stream);
    hipMemsetAsync(HAall, 0, 4ul * 524288 * sizeof(unsigned), stream);

    xenc_kernel<<<dim3((T_IN * NB) / 256), 256, 0, stream>>>(x, xenc);
    sums_kernel<<<dim3(512), 256, 0, stream>>>(A, rs, cs);
    fill_kernel<<<dim3(512), 256, 0, stream>>>(A, rs, cs, Wf, Wb);

    { // W2f = Wf@Wf, W2b = Wb@Wb (fp32, setup only)
        HopA w2 = {};
        w2.M[0] = Wf; w2.M[1] = Wb;
        w2.dst0[0] = W2f; w2.dst0[1] = W2b;
        ghop_kernel<<<dim3(8, 8, 2), 256, 0, stream>>>(w2);
    }
    { // pack hop A-operands
        WPack p;
        p.w[0] = Wf; p.w[1] = W2f; p.w[2] = Wb; p.w[3] = W2b;
        for (int m = 0; m < 4; ++m) { p.hi[m] = Whi[m]; p.lo[m] = Wlo[m]; }
        wpack_kernel<<<dim3(1024, 4), 256, 0, stream>>>(p);
    }
    { // pack lin weights
        const float* WG[6] = { Wr0, Wz0, Wn0, Wr1, Wz1, Wn1 };
        for (int g = 0; g < 6; ++g) {
            LPack p = {};
            p.W = WG[g]; p.hi = LWh[g]; p.lo = LWl[g];
            if (g < 3) { p.nseg = 5;  for (int s = 0; s < 5; ++s)  p.base[s] = 65 * s + 1; }
            else       { p.nseg = 10; for (int s = 0; s < 10; ++s) p.base[s] = 64 * s; }
            lpack_kernel<<<dim3((p.nseg * 4096 + 255) / 256), 256, 0, stream>>>(p);
        }
    }
    { // all encoder x-hops (MFMA, 192 cols = 12t x 16b)
        XHopM xa = {};
        for (int m = 0; m < 4; ++m) { xa.Ahi[m] = Whi[m]; xa.Alo[m] = Wlo[m]; }
        xa.X = xenc; xa.Y = XHE; xa.ncols = 192;
        xhop_mfma<<<dim3(3, 8, 4), 256, 0, stream>>>(xa);
    }

    auto hopcom = [&](HopM& a) {
        for (int m = 0; m < 4; ++m) { a.Ahi[m] = Whi[m]; a.Alo[m] = Wlo[m]; }
    };

    for (int t = 0; t < T_IN + T_OUT; ++t) {
        int dec = (t >= T_IN);
        int td = t - T_IN;
        const float* xcur; const float* hxs;
        if (!dec) { xcur = xenc + (size_t)t * NB; hxs = XHE + (size_t)t * 4 * NB; }
        else if (td == 0) { xcur = xenc + (size_t)(T_IN - 1) * NB; hxs = XHE + (size_t)(T_IN - 1) * 4 * NB; }
        else {
            xcur = di; hxs = HXSdec;
            XHopM xo = {};
            for (int m = 0; m < 4; ++m) { xo.Ahi[m] = Whi[m]; xo.Alo[m] = Wlo[m]; }
            xo.X = di; xo.Y = HXSdec; xo.ncols = 16;
            xhop_mfma<<<dim3(1, 8, 4), 256, 0, stream>>>(xo);
        }

        // ---- cell0: gates read HA = hops of h0 (from prev step's cell1 hop)
        LinA la = {};
        la.nseg = 5;
        la.seg[0] = h0P;
        for (int m = 0; m < 4; ++m) la.seg[1 + m] = HA_P[m];
        la.nsx = 5;
        la.sx[0] = xcur; la.sxrow[0] = 0;
        for (int m = 0; m < 4; ++m) { la.sx[1 + m] = hxs + (size_t)m * NB; la.sxrow[1 + m] = 65 * (m + 1); }
        lin_rz_mfma<<<dim3(128, 2, 2), 256, 0, stream>>>(la, LWh[0], LWl[0], Wr0, br0,
                                                         LWh[1], LWl[1], Wz0, bz0, h0, GP, Z);
        { // hops of G: MI=1, 1024 blocks
            HopM a = {}; hopcom(a);
            a.src0 = GP; a.tiles0 = 16;
            for (int m = 0; m < 4; ++m) a.dst0[m] = HG_P[m];
            hop_mfma<1><<<dim3(16, 16, 4), 256, 0, stream>>>(a);
        }
        LinA lb = la;
        lb.seg[0] = GP;
        for (int m = 0; m < 4; ++m) lb.seg[1 + m] = HG_P[m];
        lin_n_mfma<<<dim3(512), 256, 0, stream>>>(lb, 3, LWh[2], LWl[2], Wn0, bn0, Z, h0, h0P,
                                                  0, (const float*)nullptr, (const float*)nullptr,
                                                  (float*)nullptr, (float*)nullptr, 0);

        // ---- cell1: hop h0' -> HA (also serves next step's cell0), h1 -> HB
        { // dual source: MI=2, 1024 blocks
            HopM a = {}; hopcom(a);
            a.src0 = h0P; a.tiles0 = 16;
            a.src1 = h1P;
            for (int m = 0; m < 4; ++m) { a.dst0[m] = HA_P[m]; a.dst1[m] = HB_P[m]; }
            hop_mfma<2><<<dim3(32, 8, 4), 256, 0, stream>>>(a);
        }
        LinA lc = {};
        lc.nseg = 10; lc.nsx = 0;
        lc.seg[0] = h0P; lc.seg[1] = h1P;
        for (int m = 0; m < 4; ++m) { lc.seg[2 + 2 * m] = HA_P[m]; lc.seg[3 + 2 * m] = HB_P[m]; }
        lin_rz_mfma<<<dim3(128, 2, 2), 256, 0, stream>>>(lc, LWh[3], LWl[3], Wr1, br1,
                                                         LWh[4], LWl[4], Wz1, bz1, h1, GP, Z);
        {
            HopM a = {}; hopcom(a);
            a.src0 = GP; a.tiles0 = 16;
            for (int m = 0; m < 4; ++m) a.dst0[m] = HG_P[m];
            hop_mfma<1><<<dim3(16, 16, 4), 256, 0, stream>>>(a);
        }
        LinA ld = lc;
        ld.seg[1] = GP;
        for (int m = 0; m < 4; ++m) ld.seg[3 + 2 * m] = HG_P[m];
        lin_n_mfma<<<dim3(512), 256, 0, stream>>>(ld, 5, LWh[5], LWl[5], Wn1, bn1, Z, h1, h1P,
                                                  dec, Wp, bp, out, di, td);
    }
}